// Round 1
// baseline (1999.538 us; speedup 1.0000x reference)
//
#include <hip/hip_runtime.h>

#define NA 15
#define NB 32
#define DD 256
#define LDA 260   // 257 rounded up to mult of 4

// out[TM][256] = (opt relu)(act[TM][K] @ W[K][256] + bias)
// act, out in LDS. 256 threads: tr=tid>>6 (4 row-groups of TM/4), tc=tid&63 (4 cols each).
template<int TM, bool RELU>
__device__ __forceinline__ void layer256(
    const float* __restrict__ W, const float* __restrict__ bias,
    const float* act, int K, int lda,
    float* out, int ldo)
{
    constexpr int RPG = TM / 4;
    const int tid = threadIdx.x;
    const int tr = tid >> 6;
    const int tc = tid & 63;
    float acc[RPG][4];
#pragma unroll
    for (int i = 0; i < RPG; ++i) {
        acc[i][0] = 0.f; acc[i][1] = 0.f; acc[i][2] = 0.f; acc[i][3] = 0.f;
    }
    const float* wp = W + 4 * tc;
    int k = 0;
    for (; k + 4 <= K; k += 4) {
        float4 w0 = *reinterpret_cast<const float4*>(wp + (k + 0) * DD);
        float4 w1 = *reinterpret_cast<const float4*>(wp + (k + 1) * DD);
        float4 w2 = *reinterpret_cast<const float4*>(wp + (k + 2) * DD);
        float4 w3 = *reinterpret_cast<const float4*>(wp + (k + 3) * DD);
#pragma unroll
        for (int i = 0; i < RPG; ++i) {
            float4 a = *reinterpret_cast<const float4*>(act + (RPG * tr + i) * lda + k);
            acc[i][0] += a.x * w0.x + a.y * w1.x + a.z * w2.x + a.w * w3.x;
            acc[i][1] += a.x * w0.y + a.y * w1.y + a.z * w2.y + a.w * w3.y;
            acc[i][2] += a.x * w0.z + a.y * w1.z + a.z * w2.z + a.w * w3.z;
            acc[i][3] += a.x * w0.w + a.y * w1.w + a.z * w2.w + a.w * w3.w;
        }
    }
    for (; k < K; ++k) {  // K=257 remainder
        float4 w0 = *reinterpret_cast<const float4*>(wp + k * DD);
#pragma unroll
        for (int i = 0; i < RPG; ++i) {
            float a = act[(RPG * tr + i) * lda + k];
            acc[i][0] += a * w0.x; acc[i][1] += a * w0.y;
            acc[i][2] += a * w0.z; acc[i][3] += a * w0.w;
        }
    }
    float4 bb = *reinterpret_cast<const float4*>(bias + 4 * tc);
#pragma unroll
    for (int i = 0; i < RPG; ++i) {
        float4 o;
        o.x = acc[i][0] + bb.x; o.y = acc[i][1] + bb.y;
        o.z = acc[i][2] + bb.z; o.w = acc[i][3] + bb.w;
        if (RELU) {
            o.x = fmaxf(o.x, 0.f); o.y = fmaxf(o.y, 0.f);
            o.z = fmaxf(o.z, 0.f); o.w = fmaxf(o.w, 0.f);
        }
        *reinterpret_cast<float4*>(out + (RPG * tr + i) * ldo + 4 * tc) = o;
    }
}

// gout[gbase+row] = h[row][0:256] . W[:, col] + bias    (one wave per row, 2-way-free LDS banks)
template<int TM>
__device__ __forceinline__ void head1c(
    const float* h, int ldh, const float* __restrict__ W, int wstr, int col, float bias,
    float* __restrict__ gout, int gbase)
{
    const int wv = threadIdx.x >> 6;
    const int lane = threadIdx.x & 63;
    for (int rr = wv; rr < TM; rr += 4) {
        float p = 0.f;
#pragma unroll
        for (int t = 0; t < 4; ++t) {
            int k = lane + 64 * t;
            p += h[rr * ldh + k] * W[k * wstr + col];
        }
#pragma unroll
        for (int m = 1; m < 64; m <<= 1) p += __shfl_xor(p, m);
        if (lane == 0) gout[gbase + rr] = p + bias;
    }
}

// two-column head (cont logit + reward)
template<int TM>
__device__ __forceinline__ void head2c(
    const float* h, int ldh, const float* __restrict__ W, const float* __restrict__ b2,
    float* __restrict__ g0, float* __restrict__ g1, int gbase)
{
    const int wv = threadIdx.x >> 6;
    const int lane = threadIdx.x & 63;
    for (int rr = wv; rr < TM; rr += 4) {
        float p0 = 0.f, p1 = 0.f;
#pragma unroll
        for (int t = 0; t < 4; ++t) {
            int k = lane + 64 * t;
            float hv = h[rr * ldh + k];
            p0 += hv * W[k * 2 + 0];
            p1 += hv * W[k * 2 + 1];
        }
#pragma unroll
        for (int m = 1; m < 64; m <<= 1) { p0 += __shfl_xor(p0, m); p1 += __shfl_xor(p1, m); }
        if (lane == 0) { g0[gbase + rr] = p0 + b2[0]; g1[gbase + rr] = p1 + b2[1]; }
    }
}

// v = value(x) -> d_out[480..511]
__global__ __launch_bounds__(256) void value_x_kernel(
    const float* __restrict__ x,
    const float* __restrict__ emW0, const float* __restrict__ emB0,
    const float* __restrict__ emW1, const float* __restrict__ emB1,
    const float* __restrict__ emW2, const float* __restrict__ emB2,
    const float* __restrict__ vW, const float* __restrict__ vb,
    float* __restrict__ vout)
{
    constexpr int TM = 32;
    __shared__ __align__(16) float bufA[TM][DD];
    __shared__ __align__(16) float bufB[TM][DD];
    __shared__ __align__(16) float bufC[TM][DD];
    const int tid = threadIdx.x;
    for (int i = 0; i < TM; ++i) bufA[i][tid] = x[i * DD + tid];
    __syncthreads();
    layer256<TM, true >(emW0, emB0, &bufA[0][0], 256, DD, &bufB[0][0], DD); __syncthreads();
    layer256<TM, true >(emW1, emB1, &bufB[0][0], 256, DD, &bufC[0][0], DD); __syncthreads();
    layer256<TM, false>(emW2, emB2, &bufC[0][0], 256, DD, &bufB[0][0], DD); __syncthreads();
    head1c<TM>(&bufB[0][0], DD, vW, 1, 0, vb[0], vout, 0);
}

// rollout step 1: rows (b,a1) -> rews0[r], s1[r]
template<int TM>
__global__ __launch_bounds__(256) void stage1_kernel(
    const float* __restrict__ x,
    const float* __restrict__ crW0, const float* __restrict__ crB0,
    const float* __restrict__ crW1, const float* __restrict__ crB1,
    const float* __restrict__ crW2, const float* __restrict__ crB2,
    const float* __restrict__ tmW0, const float* __restrict__ tmB0,
    const float* __restrict__ tmW1, const float* __restrict__ tmB1,
    const float* __restrict__ tmW2, const float* __restrict__ tmB2,
    float* __restrict__ s1, float* __restrict__ rews0)
{
    __shared__ __align__(16) float bufA[TM][LDA];
    __shared__ __align__(16) float bufB[TM][DD];
    __shared__ __align__(16) float bufC[TM][DD];
    const int tid = threadIdx.x;
    const int row0 = blockIdx.x * TM;
    for (int i = 0; i < TM; ++i) {
        int r = row0 + i;
        bufA[i][tid] = x[(r / 15) * DD + tid];
    }
    if (tid < TM) bufA[tid][DD] = (float)((row0 + tid) % 15);
    __syncthreads();
    layer256<TM, true >(crW0, crB0, &bufA[0][0], 257, LDA, &bufB[0][0], DD); __syncthreads();
    layer256<TM, true >(crW1, crB1, &bufB[0][0], 256, DD, &bufC[0][0], DD); __syncthreads();
    head1c<TM>(&bufC[0][0], DD, crW2, 2, 1, crB2[1], rews0, row0);   // rews0 = col 1
    layer256<TM, true >(tmW0, tmB0, &bufA[0][0], 257, LDA, &bufB[0][0], DD); __syncthreads();
    layer256<TM, true >(tmW1, tmB1, &bufB[0][0], 256, DD, &bufC[0][0], DD); __syncthreads();
    layer256<TM, false>(tmW2, tmB2, &bufC[0][0], 256, DD, &bufB[0][0], DD); __syncthreads();
    for (int i = 0; i < TM; ++i) {
        int r = row0 + i;
        s1[r * DD + tid] = bufB[i][tid];
    }
}

// rollout step 2: rows (b,a1,a2) -> cont1[r], rews1[r], s2[(b,a2,a1)]
template<int TM>
__global__ __launch_bounds__(256) void stage2_kernel(
    const float* __restrict__ s1,
    const float* __restrict__ crW0, const float* __restrict__ crB0,
    const float* __restrict__ crW1, const float* __restrict__ crB1,
    const float* __restrict__ crW2, const float* __restrict__ crB2,
    const float* __restrict__ tmW0, const float* __restrict__ tmB0,
    const float* __restrict__ tmW1, const float* __restrict__ tmB1,
    const float* __restrict__ tmW2, const float* __restrict__ tmB2,
    float* __restrict__ s2, float* __restrict__ cont1, float* __restrict__ rews1)
{
    __shared__ __align__(16) float bufA[TM][LDA];
    __shared__ __align__(16) float bufB[TM][DD];
    __shared__ __align__(16) float bufC[TM][DD];
    const int tid = threadIdx.x;
    const int row0 = blockIdx.x * TM;
    for (int i = 0; i < TM; ++i) {
        int r = row0 + i;
        bufA[i][tid] = s1[(r / 15) * DD + tid];
    }
    if (tid < TM) bufA[tid][DD] = (float)((row0 + tid) % 15);
    __syncthreads();
    layer256<TM, true >(crW0, crB0, &bufA[0][0], 257, LDA, &bufB[0][0], DD); __syncthreads();
    layer256<TM, true >(crW1, crB1, &bufB[0][0], 256, DD, &bufC[0][0], DD); __syncthreads();
    head2c<TM>(&bufC[0][0], DD, crW2, crB2, cont1, rews1, row0);
    layer256<TM, true >(tmW0, tmB0, &bufA[0][0], 257, LDA, &bufB[0][0], DD); __syncthreads();
    layer256<TM, true >(tmW1, tmB1, &bufB[0][0], 256, DD, &bufC[0][0], DD); __syncthreads();
    layer256<TM, false>(tmW2, tmB2, &bufC[0][0], 256, DD, &bufB[0][0], DD); __syncthreads();
    for (int i = 0; i < TM; ++i) {
        int r = row0 + i;
        int b = r / 225;
        int a1 = (r / 15) % 15;
        int a2 = r % 15;
        s2[((b * 15 + a2) * 15 + a1) * DD + tid] = bufB[i][tid];   // moveaxis permute
    }
}

// rollout step 3 fused with value(): rows (b,a2,a1,a3) -> cont2[r], Vns3[r]
template<int TM>
__global__ __launch_bounds__(256) void stage3_kernel(
    const float* __restrict__ s2,
    const float* __restrict__ crW0, const float* __restrict__ crB0,
    const float* __restrict__ crW1, const float* __restrict__ crB1,
    const float* __restrict__ crW2, const float* __restrict__ crB2,
    const float* __restrict__ tmW0, const float* __restrict__ tmB0,
    const float* __restrict__ tmW1, const float* __restrict__ tmB1,
    const float* __restrict__ tmW2, const float* __restrict__ tmB2,
    const float* __restrict__ emW0, const float* __restrict__ emB0,
    const float* __restrict__ emW1, const float* __restrict__ emB1,
    const float* __restrict__ emW2, const float* __restrict__ emB2,
    const float* __restrict__ vW, const float* __restrict__ vb,
    float* __restrict__ cont2, float* __restrict__ Vns3)
{
    __shared__ __align__(16) float bufA[TM][LDA];
    __shared__ __align__(16) float bufB[TM][DD];
    __shared__ __align__(16) float bufC[TM][DD];
    const int tid = threadIdx.x;
    const int row0 = blockIdx.x * TM;
    for (int i = 0; i < TM; ++i) {
        int r = row0 + i;
        bufA[i][tid] = s2[(r / 15) * DD + tid];
    }
    if (tid < TM) bufA[tid][DD] = (float)((row0 + tid) % 15);
    __syncthreads();
    // cont/rew MLP -> cont2 logit (col 0)
    layer256<TM, true >(crW0, crB0, &bufA[0][0], 257, LDA, &bufB[0][0], DD); __syncthreads();
    layer256<TM, true >(crW1, crB1, &bufB[0][0], 256, DD, &bufC[0][0], DD); __syncthreads();
    head1c<TM>(&bufC[0][0], DD, crW2, 2, 0, crB2[0], cont2, row0);
    // transition MLP -> s3 row (stays in LDS)
    layer256<TM, true >(tmW0, tmB0, &bufA[0][0], 257, LDA, &bufB[0][0], DD); __syncthreads();
    layer256<TM, true >(tmW1, tmB1, &bufB[0][0], 256, DD, &bufC[0][0], DD); __syncthreads();
    layer256<TM, false>(tmW2, tmB2, &bufC[0][0], 256, DD, &bufB[0][0], DD); __syncthreads();
    // value MLP on s3
    layer256<TM, true >(emW0, emB0, &bufB[0][0], 256, DD, &bufC[0][0], DD); __syncthreads();
    layer256<TM, true >(emW1, emB1, &bufC[0][0], 256, DD, &bufA[0][0], LDA); __syncthreads();
    layer256<TM, false>(emW2, emB2, &bufA[0][0], 256, LDA, &bufC[0][0], DD); __syncthreads();
    head1c<TM>(&bufC[0][0], DD, vW, 1, 0, vb[0], Vns3, row0);
}

// masked softmax cascade + log_softmax. one block per b.
__global__ __launch_bounds__(256) void finalize_kernel(
    const float* __restrict__ Vns3, const float* __restrict__ cont2,
    const float* __restrict__ rews0, const float* __restrict__ rews1,
    const float* __restrict__ cont1, float* __restrict__ out)
{
    const int b = blockIdx.x;
    const int tid = threadIdx.x;
    __shared__ float vs2[NA][NA];
    __shared__ float vs3[NA];
    if (tid < NA * NA) {
        const int x = tid / NA, y = tid % NA;
        float vals[NA];
        float m = -INFINITY;
#pragma unroll
        for (int z = 0; z < NA; ++z) {
            int vidx = ((b * NA + y) * NA + z) * NA + x;   // V(ns3[b, a2=y, a1=z, a3=x])
            int cidx = ((b * NA + x) * NA + y) * NA + z;   // cont2 positional
            float c1 = rews0[b * NA + z] * 0.99f;
            float c2 = (c1 + rews1[(b * NA + x) * NA + z]) * 0.99f;
            float v = Vns3[vidx] * 0.970299f + c2;
            if (cont2[cidx] > 0.f) v = 0.f;                // round(sigmoid)==1
            vals[z] = v;
            m = fmaxf(m, v);
        }
        float se = 0.f, sw = 0.f;
#pragma unroll
        for (int z = 0; z < NA; ++z) {
            float e = __expf(vals[z] - m) ; // fast exp
            se += e; sw += e * vals[z];
        }
        vs2[x][y] = sw / se;
    }
    __syncthreads();
    if (tid < NA) {
        const int x = tid;
        float vals[NA];
        float m = -INFINITY;
#pragma unroll
        for (int y = 0; y < NA; ++y) {
            float v = vs2[x][y];
            if (cont1[(b * NA + x) * NA + y] > 0.f) v = 0.f;
            vals[y] = v;
            m = fmaxf(m, v);
        }
        float se = 0.f, sw = 0.f;
#pragma unroll
        for (int y = 0; y < NA; ++y) {
            float e = expf(vals[y] - m);
            se += e; sw += e * vals[y];
        }
        vs3[x] = sw / se;
    }
    __syncthreads();
    if (tid == 0) {
        float m = -INFINITY;
#pragma unroll
        for (int x = 0; x < NA; ++x) m = fmaxf(m, vs3[x]);
        float se = 0.f;
#pragma unroll
        for (int x = 0; x < NA; ++x) se += expf(vs3[x] - m);
        float l = logf(se);
#pragma unroll
        for (int x = 0; x < NA; ++x) out[b * NA + x] = vs3[x] - m - l;
    }
}

extern "C" void kernel_launch(void* const* d_in, const int* in_sizes, int n_in,
                              void* d_out, int out_size, void* d_ws, size_t ws_size,
                              hipStream_t stream)
{
    (void)in_sizes; (void)n_in; (void)out_size; (void)ws_size;
    const float* x    = (const float*)d_in[0];
    const float* emW0 = (const float*)d_in[1];
    const float* emB0 = (const float*)d_in[2];
    const float* emW1 = (const float*)d_in[3];
    const float* emB1 = (const float*)d_in[4];
    const float* emW2 = (const float*)d_in[5];
    const float* emB2 = (const float*)d_in[6];
    const float* vW   = (const float*)d_in[7];
    const float* vb   = (const float*)d_in[8];
    const float* crW0 = (const float*)d_in[9];
    const float* crB0 = (const float*)d_in[10];
    const float* crW1 = (const float*)d_in[11];
    const float* crB1 = (const float*)d_in[12];
    const float* crW2 = (const float*)d_in[13];
    const float* crB2 = (const float*)d_in[14];
    const float* tmW0 = (const float*)d_in[15];
    const float* tmB0 = (const float*)d_in[16];
    const float* tmW1 = (const float*)d_in[17];
    const float* tmB1 = (const float*)d_in[18];
    const float* tmW2 = (const float*)d_in[19];
    const float* tmB2 = (const float*)d_in[20];
    float* out = (float*)d_out;

    float* w     = (float*)d_ws;
    float* rews0 = w;                    // 480
    float* cont1 = rews0 + 480;          // 7200
    float* rews1 = cont1 + 7200;         // 7200
    float* cont2 = rews1 + 7200;         // 108000
    float* Vns3  = cont2 + 108000;       // 108000
    float* s1    = Vns3 + 108000;        // 480*256
    float* s2    = s1 + 480 * 256;       // 7200*256

    constexpr int TM = 24;
    value_x_kernel<<<1, 256, 0, stream>>>(x, emW0, emB0, emW1, emB1, emW2, emB2, vW, vb, out + NB * NA);
    stage1_kernel<TM><<<480 / TM, 256, 0, stream>>>(x,
        crW0, crB0, crW1, crB1, crW2, crB2,
        tmW0, tmB0, tmW1, tmB1, tmW2, tmB2, s1, rews0);
    stage2_kernel<TM><<<7200 / TM, 256, 0, stream>>>(s1,
        crW0, crB0, crW1, crB1, crW2, crB2,
        tmW0, tmB0, tmW1, tmB1, tmW2, tmB2, s2, cont1, rews1);
    stage3_kernel<TM><<<108000 / TM, 256, 0, stream>>>(s2,
        crW0, crB0, crW1, crB1, crW2, crB2,
        tmW0, tmB0, tmW1, tmB1, tmW2, tmB2,
        emW0, emB0, emW1, emB1, emW2, emB2, vW, vb, cont2, Vns3);
    finalize_kernel<<<NB, 256, 0, stream>>>(Vns3, cont2, rews0, rews1, cont1, out);
}

// Round 2
// 1062.447 us; speedup vs baseline: 1.8820x; 1.8820x over previous
//
#include <hip/hip_runtime.h>

#define NA 15
#define NB 32
#define DD 256
#define LDA 260   // 257 rounded up to mult of 4 (fp32 stage1/2 kernels)
#define PL 65536  // shorts per weight plane (8 slices x 256 rows x 32 k)

using bf16x8 = __attribute__((ext_vector_type(8))) short;
using f32x4  = __attribute__((ext_vector_type(4))) float;

__device__ __forceinline__ unsigned short f2bf(float f){
  unsigned int u = __float_as_uint(f);
  u = u + 0x7fffu + ((u >> 16) & 1u);
  return (unsigned short)(u >> 16);
}
__device__ __forceinline__ float bf2f(unsigned short h){
  return __uint_as_float(((unsigned int)h) << 16);
}
__device__ __forceinline__ void gl_lds16(const void* g, void* l){
  __builtin_amdgcn_global_load_lds(
      (const __attribute__((address_space(1))) void*)g,
      (__attribute__((address_space(3))) void*)l, 16, 0, 0);
}

// ---------------------------------------------------------------------------
// fp32 VALU kernels (round-1, unchanged): value(x), stage1, stage2, finalize
// ---------------------------------------------------------------------------
template<int TM, bool RELU>
__device__ __forceinline__ void layer256(
    const float* __restrict__ W, const float* __restrict__ bias,
    const float* act, int K, int lda, float* out, int ldo)
{
    constexpr int RPG = TM / 4;
    const int tid = threadIdx.x;
    const int tr = tid >> 6;
    const int tc = tid & 63;
    float acc[RPG][4];
#pragma unroll
    for (int i = 0; i < RPG; ++i) { acc[i][0]=0.f; acc[i][1]=0.f; acc[i][2]=0.f; acc[i][3]=0.f; }
    const float* wp = W + 4 * tc;
    int k = 0;
    for (; k + 4 <= K; k += 4) {
        float4 w0 = *reinterpret_cast<const float4*>(wp + (k + 0) * DD);
        float4 w1 = *reinterpret_cast<const float4*>(wp + (k + 1) * DD);
        float4 w2 = *reinterpret_cast<const float4*>(wp + (k + 2) * DD);
        float4 w3 = *reinterpret_cast<const float4*>(wp + (k + 3) * DD);
#pragma unroll
        for (int i = 0; i < RPG; ++i) {
            float4 a = *reinterpret_cast<const float4*>(act + (RPG * tr + i) * lda + k);
            acc[i][0] += a.x * w0.x + a.y * w1.x + a.z * w2.x + a.w * w3.x;
            acc[i][1] += a.x * w0.y + a.y * w1.y + a.z * w2.y + a.w * w3.y;
            acc[i][2] += a.x * w0.z + a.y * w1.z + a.z * w2.z + a.w * w3.z;
            acc[i][3] += a.x * w0.w + a.y * w1.w + a.z * w2.w + a.w * w3.w;
        }
    }
    for (; k < K; ++k) {
        float4 w0 = *reinterpret_cast<const float4*>(wp + k * DD);
#pragma unroll
        for (int i = 0; i < RPG; ++i) {
            float a = act[(RPG * tr + i) * lda + k];
            acc[i][0] += a * w0.x; acc[i][1] += a * w0.y;
            acc[i][2] += a * w0.z; acc[i][3] += a * w0.w;
        }
    }
    float4 bb = *reinterpret_cast<const float4*>(bias + 4 * tc);
#pragma unroll
    for (int i = 0; i < RPG; ++i) {
        float4 o;
        o.x = acc[i][0] + bb.x; o.y = acc[i][1] + bb.y;
        o.z = acc[i][2] + bb.z; o.w = acc[i][3] + bb.w;
        if (RELU) {
            o.x = fmaxf(o.x, 0.f); o.y = fmaxf(o.y, 0.f);
            o.z = fmaxf(o.z, 0.f); o.w = fmaxf(o.w, 0.f);
        }
        *reinterpret_cast<float4*>(out + (RPG * tr + i) * ldo + 4 * tc) = o;
    }
}

template<int TM>
__device__ __forceinline__ void head1c(
    const float* h, int ldh, const float* __restrict__ W, int wstr, int col, float bias,
    float* __restrict__ gout, int gbase)
{
    const int wv = threadIdx.x >> 6;
    const int lane = threadIdx.x & 63;
    for (int rr = wv; rr < TM; rr += 4) {
        float p = 0.f;
#pragma unroll
        for (int t = 0; t < 4; ++t) {
            int k = lane + 64 * t;
            p += h[rr * ldh + k] * W[k * wstr + col];
        }
#pragma unroll
        for (int m = 1; m < 64; m <<= 1) p += __shfl_xor(p, m);
        if (lane == 0) gout[gbase + rr] = p + bias;
    }
}

template<int TM>
__device__ __forceinline__ void head2c(
    const float* h, int ldh, const float* __restrict__ W, const float* __restrict__ b2,
    float* __restrict__ g0, float* __restrict__ g1, int gbase)
{
    const int wv = threadIdx.x >> 6;
    const int lane = threadIdx.x & 63;
    for (int rr = wv; rr < TM; rr += 4) {
        float p0 = 0.f, p1 = 0.f;
#pragma unroll
        for (int t = 0; t < 4; ++t) {
            int k = lane + 64 * t;
            float hv = h[rr * ldh + k];
            p0 += hv * W[k * 2 + 0];
            p1 += hv * W[k * 2 + 1];
        }
#pragma unroll
        for (int m = 1; m < 64; m <<= 1) { p0 += __shfl_xor(p0, m); p1 += __shfl_xor(p1, m); }
        if (lane == 0) { g0[gbase + rr] = p0 + b2[0]; g1[gbase + rr] = p1 + b2[1]; }
    }
}

__global__ __launch_bounds__(256) void value_x_kernel(
    const float* __restrict__ x,
    const float* __restrict__ emW0, const float* __restrict__ emB0,
    const float* __restrict__ emW1, const float* __restrict__ emB1,
    const float* __restrict__ emW2, const float* __restrict__ emB2,
    const float* __restrict__ vW, const float* __restrict__ vb,
    float* __restrict__ vout)
{
    constexpr int TM = 32;
    __shared__ __align__(16) float bufA[TM][DD];
    __shared__ __align__(16) float bufB[TM][DD];
    __shared__ __align__(16) float bufC[TM][DD];
    const int tid = threadIdx.x;
    for (int i = 0; i < TM; ++i) bufA[i][tid] = x[i * DD + tid];
    __syncthreads();
    layer256<TM, true >(emW0, emB0, &bufA[0][0], 256, DD, &bufB[0][0], DD); __syncthreads();
    layer256<TM, true >(emW1, emB1, &bufB[0][0], 256, DD, &bufC[0][0], DD); __syncthreads();
    layer256<TM, false>(emW2, emB2, &bufC[0][0], 256, DD, &bufB[0][0], DD); __syncthreads();
    head1c<TM>(&bufB[0][0], DD, vW, 1, 0, vb[0], vout, 0);
}

template<int TM>
__global__ __launch_bounds__(256) void stage1_kernel(
    const float* __restrict__ x,
    const float* __restrict__ crW0, const float* __restrict__ crB0,
    const float* __restrict__ crW1, const float* __restrict__ crB1,
    const float* __restrict__ crW2, const float* __restrict__ crB2,
    const float* __restrict__ tmW0, const float* __restrict__ tmB0,
    const float* __restrict__ tmW1, const float* __restrict__ tmB1,
    const float* __restrict__ tmW2, const float* __restrict__ tmB2,
    float* __restrict__ s1, float* __restrict__ rews0)
{
    __shared__ __align__(16) float bufA[TM][LDA];
    __shared__ __align__(16) float bufB[TM][DD];
    __shared__ __align__(16) float bufC[TM][DD];
    const int tid = threadIdx.x;
    const int row0 = blockIdx.x * TM;
    for (int i = 0; i < TM; ++i) bufA[i][tid] = x[((row0 + i) / 15) * DD + tid];
    if (tid < TM) bufA[tid][DD] = (float)((row0 + tid) % 15);
    __syncthreads();
    layer256<TM, true >(crW0, crB0, &bufA[0][0], 257, LDA, &bufB[0][0], DD); __syncthreads();
    layer256<TM, true >(crW1, crB1, &bufB[0][0], 256, DD, &bufC[0][0], DD); __syncthreads();
    head1c<TM>(&bufC[0][0], DD, crW2, 2, 1, crB2[1], rews0, row0);
    layer256<TM, true >(tmW0, tmB0, &bufA[0][0], 257, LDA, &bufB[0][0], DD); __syncthreads();
    layer256<TM, true >(tmW1, tmB1, &bufB[0][0], 256, DD, &bufC[0][0], DD); __syncthreads();
    layer256<TM, false>(tmW2, tmB2, &bufC[0][0], 256, DD, &bufB[0][0], DD); __syncthreads();
    for (int i = 0; i < TM; ++i) s1[(row0 + i) * DD + tid] = bufB[i][tid];
}

template<int TM>
__global__ __launch_bounds__(256) void stage2_kernel(
    const float* __restrict__ s1,
    const float* __restrict__ crW0, const float* __restrict__ crB0,
    const float* __restrict__ crW1, const float* __restrict__ crB1,
    const float* __restrict__ crW2, const float* __restrict__ crB2,
    const float* __restrict__ tmW0, const float* __restrict__ tmB0,
    const float* __restrict__ tmW1, const float* __restrict__ tmB1,
    const float* __restrict__ tmW2, const float* __restrict__ tmB2,
    float* __restrict__ s2, float* __restrict__ cont1, float* __restrict__ rews1)
{
    __shared__ __align__(16) float bufA[TM][LDA];
    __shared__ __align__(16) float bufB[TM][DD];
    __shared__ __align__(16) float bufC[TM][DD];
    const int tid = threadIdx.x;
    const int row0 = blockIdx.x * TM;
    for (int i = 0; i < TM; ++i) bufA[i][tid] = s1[((row0 + i) / 15) * DD + tid];
    if (tid < TM) bufA[tid][DD] = (float)((row0 + tid) % 15);
    __syncthreads();
    layer256<TM, true >(crW0, crB0, &bufA[0][0], 257, LDA, &bufB[0][0], DD); __syncthreads();
    layer256<TM, true >(crW1, crB1, &bufB[0][0], 256, DD, &bufC[0][0], DD); __syncthreads();
    head2c<TM>(&bufC[0][0], DD, crW2, crB2, cont1, rews1, row0);
    layer256<TM, true >(tmW0, tmB0, &bufA[0][0], 257, LDA, &bufB[0][0], DD); __syncthreads();
    layer256<TM, true >(tmW1, tmB1, &bufB[0][0], 256, DD, &bufC[0][0], DD); __syncthreads();
    layer256<TM, false>(tmW2, tmB2, &bufC[0][0], 256, DD, &bufB[0][0], DD); __syncthreads();
    for (int i = 0; i < TM; ++i) {
        int r = row0 + i;
        int b = r / 225, a1 = (r / 15) % 15, a2 = r % 15;
        s2[((b * 15 + a2) * 15 + a1) * DD + tid] = bufB[i][tid];
    }
}

__global__ __launch_bounds__(256) void finalize_kernel(
    const float* __restrict__ Vns3, const float* __restrict__ cont2,
    const float* __restrict__ rews0, const float* __restrict__ rews1,
    const float* __restrict__ cont1, float* __restrict__ out)
{
    const int b = blockIdx.x;
    const int tid = threadIdx.x;
    __shared__ float vs2[NA][NA];
    __shared__ float vs3[NA];
    if (tid < NA * NA) {
        const int x = tid / NA, y = tid % NA;
        float vals[NA];
        float m = -INFINITY;
#pragma unroll
        for (int z = 0; z < NA; ++z) {
            int vidx = ((b * NA + y) * NA + z) * NA + x;
            int cidx = ((b * NA + x) * NA + y) * NA + z;
            float c1 = rews0[b * NA + z] * 0.99f;
            float c2 = (c1 + rews1[(b * NA + x) * NA + z]) * 0.99f;
            float v = Vns3[vidx] * 0.970299f + c2;
            if (cont2[cidx] > 0.f) v = 0.f;
            vals[z] = v;
            m = fmaxf(m, v);
        }
        float se = 0.f, sw = 0.f;
#pragma unroll
        for (int z = 0; z < NA; ++z) { float e = expf(vals[z] - m); se += e; sw += e * vals[z]; }
        vs2[x][y] = sw / se;
    }
    __syncthreads();
    if (tid < NA) {
        const int x = tid;
        float vals[NA];
        float m = -INFINITY;
#pragma unroll
        for (int y = 0; y < NA; ++y) {
            float v = vs2[x][y];
            if (cont1[(b * NA + x) * NA + y] > 0.f) v = 0.f;
            vals[y] = v;
            m = fmaxf(m, v);
        }
        float se = 0.f, sw = 0.f;
#pragma unroll
        for (int y = 0; y < NA; ++y) { float e = expf(vals[y] - m); se += e; sw += e * vals[y]; }
        vs3[x] = sw / se;
    }
    __syncthreads();
    if (tid == 0) {
        float m = -INFINITY;
#pragma unroll
        for (int x = 0; x < NA; ++x) m = fmaxf(m, vs3[x]);
        float se = 0.f;
#pragma unroll
        for (int x = 0; x < NA; ++x) se += expf(vs3[x] - m);
        float l = logf(se);
#pragma unroll
        for (int x = 0; x < NA; ++x) out[b * NA + x] = vs3[x] - m - l;
    }
}

// ---------------------------------------------------------------------------
// prep: transpose + bf16-split the 256x256 blocks of the 8 MLP matrices into
// MFMA-fragment-linear planes: plane[kk][outcol][kidx], kk=k>>5, kidx=k&31.
// planes 0-2: crW0 h/m/l; 3-5: crW1 h/m/l; 6,7: tmW0 h/l; 8,9: tmW1; 10,11: tmW2;
// 12,13: emW0; 14,15: emW1; 16,17: emW2.
// ---------------------------------------------------------------------------
__global__ __launch_bounds__(256) void prep_kernel(
    const float* __restrict__ crW0, const float* __restrict__ crW1,
    const float* __restrict__ tmW0, const float* __restrict__ tmW1,
    const float* __restrict__ tmW2, const float* __restrict__ emW0,
    const float* __restrict__ emW1, const float* __restrict__ emW2,
    short* __restrict__ planes)
{
    const int mat = blockIdx.x >> 3;
    const int kk  = blockIdx.x & 7;
    const float* W; int pbase; int ns;
    switch (mat) {
        case 0: W = crW0; pbase = 0;  ns = 3; break;
        case 1: W = crW1; pbase = 3;  ns = 3; break;
        case 2: W = tmW0; pbase = 6;  ns = 2; break;
        case 3: W = tmW1; pbase = 8;  ns = 2; break;
        case 4: W = tmW2; pbase = 10; ns = 2; break;
        case 5: W = emW0; pbase = 12; ns = 2; break;
        case 6: W = emW1; pbase = 14; ns = 2; break;
        default: W = emW2; pbase = 16; ns = 2; break;
    }
    const int col = threadIdx.x;
    short bh[32], bm[32], bl[32];
#pragma unroll
    for (int j = 0; j < 32; ++j) {
        float w = W[(kk * 32 + j) * 256 + col];
        unsigned short h = f2bf(w); float fh = bf2f(h);
        float r1 = w - fh;
        if (ns == 3) {
            unsigned short m = f2bf(r1); float fm = bf2f(m);
            bm[j] = (short)m; bl[j] = (short)f2bf(r1 - fm);
        } else {
            bm[j] = 0; bl[j] = (short)f2bf(r1);
        }
        bh[j] = (short)h;
    }
    short* pH = planes + (size_t)pbase * PL + kk * 8192 + col * 32;
#pragma unroll
    for (int j = 0; j < 32; j += 4) *(short4*)(pH + j) = make_short4(bh[j], bh[j+1], bh[j+2], bh[j+3]);
    short* pN = planes + (size_t)(pbase + 1) * PL + kk * 8192 + col * 32;   // m (3-way) or l (2-way)
    const short* s1p = (ns == 3) ? bm : bl;
#pragma unroll
    for (int j = 0; j < 32; j += 4) *(short4*)(pN + j) = make_short4(s1p[j], s1p[j+1], s1p[j+2], s1p[j+3]);
    if (ns == 3) {
        short* pL = planes + (size_t)(pbase + 2) * PL + kk * 8192 + col * 32;
#pragma unroll
        for (int j = 0; j < 32; j += 4) *(short4*)(pL + j) = make_short4(bl[j], bl[j+1], bl[j+2], bl[j+3]);
    }
}

// ---------------------------------------------------------------------------
// MFMA stage-3 kernels
// ---------------------------------------------------------------------------
__device__ __forceinline__ void stage2w(const short* plH, const short* plL, int kk,
                                        short* dH, short* dL, int tid)
{
    const int wv = tid >> 6, ln = tid & 63;
    const char* sH = (const char*)(plH + kk * 8192);
    const char* sL = (const char*)(plL + kk * 8192);
#pragma unroll
    for (int c = 0; c < 4; ++c) {
        const int off = (wv * 4 + c) * 1024;
        gl_lds16(sH + off + ln * 16, (char*)dH + off);
        gl_lds16(sL + off + ln * 16, (char*)dL + off);
    }
}

__device__ __forceinline__ void stage3w(const short* plH, const short* plM, const short* plL,
                                        int kk, short* dH, short* dM, short* dL, int tid)
{
    const int wv = tid >> 6, ln = tid & 63;
    const char* sH = (const char*)(plH + kk * 8192);
    const char* sM = (const char*)(plM + kk * 8192);
    const char* sL = (const char*)(plL + kk * 8192);
#pragma unroll
    for (int c = 0; c < 4; ++c) {
        const int off = (wv * 4 + c) * 1024;
        gl_lds16(sH + off + ln * 16, (char*)dH + off);
        gl_lds16(sM + off + ln * 16, (char*)dM + off);
        gl_lds16(sL + off + ln * 16, (char*)dL + off);
    }
}

// K3b layer: out[64][256] = act[64][256] @ W + b ; 2-way split, 3 MFMA passes.
template<bool RELU, bool RANK1, bool HEAD, bool WRITEACT>
__device__ __forceinline__ void layer3b(
    const short* __restrict__ plH, const short* __restrict__ plL,
    const float* __restrict__ bias, const float* __restrict__ w0r256,
    const float* __restrict__ headW, int headStride, const float* __restrict__ headB,
    float* __restrict__ headOut, int row0,
    short* actH, short* actL, short* wb, float* hred)
{
    const int tid = threadIdx.x;
    const int ln15 = tid & 15, lng = (tid >> 4) & 3, wv = tid >> 6;
    f32x4 acc[4][4];
#pragma unroll
    for (int a = 0; a < 4; ++a)
#pragma unroll
        for (int b = 0; b < 4; ++b) acc[a][b] = f32x4{0.f, 0.f, 0.f, 0.f};

    stage2w(plH, plL, 0, wb + 0 * 8192, wb + 1 * 8192, tid);
    asm volatile("s_waitcnt vmcnt(0)" ::: "memory");
    __syncthreads();
#pragma unroll
    for (int kk = 0; kk < 8; ++kk) {
        const short* cH = wb + ((kk & 1) * 2 + 0) * 8192;
        const short* cL = wb + ((kk & 1) * 2 + 1) * 8192;
        if (kk < 7)
            stage2w(plH, plL, kk + 1, wb + (((kk + 1) & 1) * 2 + 0) * 8192,
                    wb + (((kk + 1) & 1) * 2 + 1) * 8192, tid);
        bf16x8 aH[4], aL[4], bH[4], bL[4];
#pragma unroll
        for (int ct = 0; ct < 4; ++ct) {
            int nrow = wv * 64 + ct * 16 + ln15;
            aH[ct] = *(const bf16x8*)(cH + nrow * 32 + lng * 8);
            aL[ct] = *(const bf16x8*)(cL + nrow * 32 + lng * 8);
        }
#pragma unroll
        for (int rt = 0; rt < 4; ++rt) {
            int off = (rt * 16 + ln15) * 264 + kk * 32 + lng * 8;
            bH[rt] = *(const bf16x8*)(actH + off);
            bL[rt] = *(const bf16x8*)(actL + off);
        }
#pragma unroll
        for (int ct = 0; ct < 4; ++ct)
#pragma unroll
            for (int rt = 0; rt < 4; ++rt) {
                acc[ct][rt] = __builtin_amdgcn_mfma_f32_16x16x32_bf16(aH[ct], bH[rt], acc[ct][rt], 0, 0, 0);
                acc[ct][rt] = __builtin_amdgcn_mfma_f32_16x16x32_bf16(aH[ct], bL[rt], acc[ct][rt], 0, 0, 0);
                acc[ct][rt] = __builtin_amdgcn_mfma_f32_16x16x32_bf16(aL[ct], bH[rt], acc[ct][rt], 0, 0, 0);
            }
        if (kk < 7) { asm volatile("s_waitcnt vmcnt(0)" ::: "memory"); __syncthreads(); }
    }
    __syncthreads();   // all act reads done before in-place overwrite

    float hp[4] = {0.f, 0.f, 0.f, 0.f};
#pragma unroll
    for (int ct = 0; ct < 4; ++ct) {
        const int colb = wv * 64 + ct * 16 + lng * 4;
        const float4 bb = *(const float4*)(bias + colb);
        float4 wr;
        if (RANK1) wr = *(const float4*)(w0r256 + colb);
#pragma unroll
        for (int rt = 0; rt < 4; ++rt) {
            f32x4 v = acc[ct][rt];
            if (RANK1) {
                float a = (float)((row0 + rt * 16 + ln15) % 15);
                v[0] += a * wr.x; v[1] += a * wr.y; v[2] += a * wr.z; v[3] += a * wr.w;
            }
            v[0] += bb.x; v[1] += bb.y; v[2] += bb.z; v[3] += bb.w;
            if (RELU) {
#pragma unroll
                for (int j = 0; j < 4; ++j) v[j] = fmaxf(v[j], 0.f);
            }
            if (HEAD) {
#pragma unroll
                for (int j = 0; j < 4; ++j) hp[rt] += v[j] * headW[(colb + j) * headStride];
            }
            if (WRITEACT) {
                unsigned short hs[4], ls[4];
#pragma unroll
                for (int j = 0; j < 4; ++j) {
                    unsigned short h = f2bf(v[j]); float fh = bf2f(h);
                    hs[j] = h; ls[j] = f2bf(v[j] - fh);
                }
                const int ao = (rt * 16 + ln15) * 264 + colb;
                *(short4*)(actH + ao) = make_short4(hs[0], hs[1], hs[2], hs[3]);
                *(short4*)(actL + ao) = make_short4(ls[0], ls[1], ls[2], ls[3]);
            }
        }
    }
    if constexpr (HEAD) {
#pragma unroll
        for (int rt = 0; rt < 4; ++rt) {
            hp[rt] += __shfl_xor(hp[rt], 16);
            hp[rt] += __shfl_xor(hp[rt], 32);
        }
        if (lng == 0) {
#pragma unroll
            for (int rt = 0; rt < 4; ++rt) hred[wv * 64 + rt * 16 + ln15] = hp[rt];
        }
        __syncthreads();
        if (tid < 64) {
            float s = hred[tid] + hred[64 + tid] + hred[128 + tid] + hred[192 + tid] + headB[0];
            int r = row0 + tid;
            if (r < 108000) headOut[r] = s;
        }
    }
    if constexpr (WRITEACT) __syncthreads();
}

// K3a layer: 3-way split, 6 MFMA passes (fp32-grade, feeds the cont2 mask).
template<bool RANK1, bool HEAD, bool WRITEACT>
__device__ __forceinline__ void layer3a(
    const short* __restrict__ plH, const short* __restrict__ plM, const short* __restrict__ plL,
    const float* __restrict__ bias, const float* __restrict__ w0r256,
    const float* __restrict__ headW, int headStride, const float* __restrict__ headB,
    float* __restrict__ headOut, int row0,
    short* actH, short* actM, short* actL, short* wb, float* hred)
{
    const int tid = threadIdx.x;
    const int ln15 = tid & 15, lng = (tid >> 4) & 3, wv = tid >> 6;
    f32x4 acc[4][2];
#pragma unroll
    for (int a = 0; a < 4; ++a) { acc[a][0] = f32x4{0.f,0.f,0.f,0.f}; acc[a][1] = f32x4{0.f,0.f,0.f,0.f}; }

    stage3w(plH, plM, plL, 0, wb, wb + 8192, wb + 2 * 8192, tid);
    asm volatile("s_waitcnt vmcnt(0)" ::: "memory");
    __syncthreads();
#pragma unroll
    for (int kk = 0; kk < 8; ++kk) {
        const short* cH = wb + ((kk & 1) * 3 + 0) * 8192;
        const short* cM = wb + ((kk & 1) * 3 + 1) * 8192;
        const short* cL = wb + ((kk & 1) * 3 + 2) * 8192;
        if (kk < 7)
            stage3w(plH, plM, plL, kk + 1,
                    wb + (((kk + 1) & 1) * 3 + 0) * 8192,
                    wb + (((kk + 1) & 1) * 3 + 1) * 8192,
                    wb + (((kk + 1) & 1) * 3 + 2) * 8192, tid);
        bf16x8 wH[4], wM[4], wL[4], xH[2], xM[2], xL[2];
#pragma unroll
        for (int ct = 0; ct < 4; ++ct) {
            int nrow = wv * 64 + ct * 16 + ln15;
            wH[ct] = *(const bf16x8*)(cH + nrow * 32 + lng * 8);
            wM[ct] = *(const bf16x8*)(cM + nrow * 32 + lng * 8);
            wL[ct] = *(const bf16x8*)(cL + nrow * 32 + lng * 8);
        }
#pragma unroll
        for (int rt = 0; rt < 2; ++rt) {
            int off = (rt * 16 + ln15) * 264 + kk * 32 + lng * 8;
            xH[rt] = *(const bf16x8*)(actH + off);
            xM[rt] = *(const bf16x8*)(actM + off);
            xL[rt] = *(const bf16x8*)(actL + off);
        }
#pragma unroll
        for (int ct = 0; ct < 4; ++ct)
#pragma unroll
            for (int rt = 0; rt < 2; ++rt) {
                acc[ct][rt] = __builtin_amdgcn_mfma_f32_16x16x32_bf16(wH[ct], xH[rt], acc[ct][rt], 0, 0, 0);
                acc[ct][rt] = __builtin_amdgcn_mfma_f32_16x16x32_bf16(wH[ct], xM[rt], acc[ct][rt], 0, 0, 0);
                acc[ct][rt] = __builtin_amdgcn_mfma_f32_16x16x32_bf16(wM[ct], xH[rt], acc[ct][rt], 0, 0, 0);
                acc[ct][rt] = __builtin_amdgcn_mfma_f32_16x16x32_bf16(wM[ct], xM[rt], acc[ct][rt], 0, 0, 0);
                acc[ct][rt] = __builtin_amdgcn_mfma_f32_16x16x32_bf16(wH[ct], xL[rt], acc[ct][rt], 0, 0, 0);
                acc[ct][rt] = __builtin_amdgcn_mfma_f32_16x16x32_bf16(wL[ct], xH[rt], acc[ct][rt], 0, 0, 0);
            }
        if (kk < 7) { asm volatile("s_waitcnt vmcnt(0)" ::: "memory"); __syncthreads(); }
    }
    __syncthreads();

    float hp[2] = {0.f, 0.f};
#pragma unroll
    for (int ct = 0; ct < 4; ++ct) {
        const int colb = wv * 64 + ct * 16 + lng * 4;
        const float4 bb = *(const float4*)(bias + colb);
        float4 wr;
        if (RANK1) wr = *(const float4*)(w0r256 + colb);
#pragma unroll
        for (int rt = 0; rt < 2; ++rt) {
            f32x4 v = acc[ct][rt];
            if (RANK1) {
                float a = (float)((row0 + rt * 16 + ln15) % 15);
                v[0] += a * wr.x; v[1] += a * wr.y; v[2] += a * wr.z; v[3] += a * wr.w;
            }
            v[0] += bb.x; v[1] += bb.y; v[2] += bb.z; v[3] += bb.w;
#pragma unroll
            for (int j = 0; j < 4; ++j) v[j] = fmaxf(v[j], 0.f);   // both cr layers are relu
            if (HEAD) {
#pragma unroll
                for (int j = 0; j < 4; ++j) hp[rt] += v[j] * headW[(colb + j) * headStride];
            }
            if (WRITEACT) {
                unsigned short hs[4], ms[4], ls[4];
#pragma unroll
                for (int j = 0; j < 4; ++j) {
                    unsigned short h = f2bf(v[j]); float fh = bf2f(h);
                    float r1 = v[j] - fh;
                    unsigned short m = f2bf(r1); float fm = bf2f(m);
                    hs[j] = h; ms[j] = m; ls[j] = f2bf(r1 - fm);
                }
                const int ao = (rt * 16 + ln15) * 264 + colb;
                *(short4*)(actH + ao) = make_short4(hs[0], hs[1], hs[2], hs[3]);
                *(short4*)(actM + ao) = make_short4(ms[0], ms[1], ms[2], ms[3]);
                *(short4*)(actL + ao) = make_short4(ls[0], ls[1], ls[2], ls[3]);
            }
        }
    }
    if constexpr (HEAD) {
#pragma unroll
        for (int rt = 0; rt < 2; ++rt) {
            hp[rt] += __shfl_xor(hp[rt], 16);
            hp[rt] += __shfl_xor(hp[rt], 32);
        }
        if (lng == 0) {
#pragma unroll
            for (int rt = 0; rt < 2; ++rt) hred[wv * 32 + rt * 16 + ln15] = hp[rt];
        }
        __syncthreads();
        if (tid < 32) {
            float s = hred[tid] + hred[32 + tid] + hred[64 + tid] + hred[96 + tid] + headB[0];
            int r = row0 + tid;
            if (r < 108000) headOut[r] = s;
        }
    }
    if constexpr (WRITEACT) __syncthreads();
}

__global__ __launch_bounds__(256, 1) void k3b_kernel(
    const float* __restrict__ s2, const short* __restrict__ planes,
    const float* __restrict__ tmW0,
    const float* __restrict__ tmB0, const float* __restrict__ tmB1, const float* __restrict__ tmB2,
    const float* __restrict__ emB0, const float* __restrict__ emB1, const float* __restrict__ emB2,
    const float* __restrict__ vW, const float* __restrict__ vb,
    float* __restrict__ Vns3)
{
    __shared__ short actH[64 * 264];
    __shared__ short actL[64 * 264];
    __shared__ short wb[4 * 8192];
    __shared__ float hred[256];
    const int tid = threadIdx.x;
    const int row0 = blockIdx.x * 64;
    const int wv = tid >> 6, ln = tid & 63;
    for (int i = wv * 16; i < wv * 16 + 16; ++i) {
        int srow = (row0 + i) / 15; if (srow > 7199) srow = 7199;
#pragma unroll
        for (int t = 0; t < 4; ++t) {
            int c = ln + 64 * t;
            float s = s2[srow * 256 + c];
            unsigned short h = f2bf(s); float fh = bf2f(h);
            actH[i * 264 + c] = (short)h;
            actL[i * 264 + c] = (short)f2bf(s - fh);
        }
    }
    __syncthreads();
    const short* P = planes;
    layer3b<true,  true,  false, true >(P + 6 * PL,  P + 7 * PL,  tmB0, tmW0 + 65536,
                                        nullptr, 0, nullptr, nullptr, row0, actH, actL, wb, hred);
    layer3b<true,  false, false, true >(P + 8 * PL,  P + 9 * PL,  tmB1, nullptr,
                                        nullptr, 0, nullptr, nullptr, row0, actH, actL, wb, hred);
    layer3b<false, false, false, true >(P + 10 * PL, P + 11 * PL, tmB2, nullptr,
                                        nullptr, 0, nullptr, nullptr, row0, actH, actL, wb, hred);
    layer3b<true,  false, false, true >(P + 12 * PL, P + 13 * PL, emB0, nullptr,
                                        nullptr, 0, nullptr, nullptr, row0, actH, actL, wb, hred);
    layer3b<true,  false, false, true >(P + 14 * PL, P + 15 * PL, emB1, nullptr,
                                        nullptr, 0, nullptr, nullptr, row0, actH, actL, wb, hred);
    layer3b<false, false, true,  false>(P + 16 * PL, P + 17 * PL, emB2, nullptr,
                                        vW, 1, vb, Vns3, row0, actH, actL, wb, hred);
}

__global__ __launch_bounds__(256, 1) void k3a_kernel(
    const float* __restrict__ s2, const short* __restrict__ planes,
    const float* __restrict__ crW0, const float* __restrict__ crB0,
    const float* __restrict__ crB1, const float* __restrict__ crW2,
    const float* __restrict__ crB2, float* __restrict__ cont2)
{
    __shared__ short actH[32 * 264];
    __shared__ short actM[32 * 264];
    __shared__ short actL[32 * 264];
    __shared__ short wb[6 * 8192];
    __shared__ float hred[128];
    const int tid = threadIdx.x;
    const int row0 = blockIdx.x * 32;
    const int wv = tid >> 6, ln = tid & 63;
    for (int i = wv * 8; i < wv * 8 + 8; ++i) {
        int srow = (row0 + i) / 15; if (srow > 7199) srow = 7199;
#pragma unroll
        for (int t = 0; t < 4; ++t) {
            int c = ln + 64 * t;
            float s = s2[srow * 256 + c];
            unsigned short h = f2bf(s); float fh = bf2f(h);
            float r1 = s - fh;
            unsigned short m = f2bf(r1); float fm = bf2f(m);
            actH[i * 264 + c] = (short)h;
            actM[i * 264 + c] = (short)m;
            actL[i * 264 + c] = (short)f2bf(r1 - fm);
        }
    }
    __syncthreads();
    const short* P = planes;
    layer3a<true,  false, true >(P + 0 * PL, P + 1 * PL, P + 2 * PL, crB0, crW0 + 65536,
                                 nullptr, 0, nullptr, nullptr, row0, actH, actM, actL, wb, hred);
    layer3a<false, true,  false>(P + 3 * PL, P + 4 * PL, P + 5 * PL, crB1, nullptr,
                                 crW2, 2, crB2, cont2, row0, actH, actM, actL, wb, hred);
}

extern "C" void kernel_launch(void* const* d_in, const int* in_sizes, int n_in,
                              void* d_out, int out_size, void* d_ws, size_t ws_size,
                              hipStream_t stream)
{
    (void)in_sizes; (void)n_in; (void)out_size; (void)ws_size;
    const float* x    = (const float*)d_in[0];
    const float* emW0 = (const float*)d_in[1];
    const float* emB0 = (const float*)d_in[2];
    const float* emW1 = (const float*)d_in[3];
    const float* emB1 = (const float*)d_in[4];
    const float* emW2 = (const float*)d_in[5];
    const float* emB2 = (const float*)d_in[6];
    const float* vW   = (const float*)d_in[7];
    const float* vb   = (const float*)d_in[8];
    const float* crW0 = (const float*)d_in[9];
    const float* crB0 = (const float*)d_in[10];
    const float* crW1 = (const float*)d_in[11];
    const float* crB1 = (const float*)d_in[12];
    const float* crW2 = (const float*)d_in[13];
    const float* crB2 = (const float*)d_in[14];
    const float* tmW0 = (const float*)d_in[15];
    const float* tmB0 = (const float*)d_in[16];
    const float* tmW1 = (const float*)d_in[17];
    const float* tmB1 = (const float*)d_in[18];
    const float* tmW2 = (const float*)d_in[19];
    const float* tmB2 = (const float*)d_in[20];
    float* out = (float*)d_out;

    float* w     = (float*)d_ws;
    float* rews0 = w;                     // 480
    float* cont1 = rews0 + 480;           // 7200
    float* rews1 = cont1 + 7200;          // 7200
    float* cont2 = rews1 + 7200;          // 108000
    float* Vns3  = cont2 + 108000;        // 108000
    float* s1    = Vns3 + 108000;         // 480*256
    float* s2    = s1 + 480 * 256;        // 7200*256
    short* planes = (short*)(s2 + 7200 * 256);  // 18 * 65536 shorts = 2.25 MB

    constexpr int TM = 24;
    prep_kernel<<<64, 256, 0, stream>>>(crW0, crW1, tmW0, tmW1, tmW2, emW0, emW1, emW2, planes);
    value_x_kernel<<<1, 256, 0, stream>>>(x, emW0, emB0, emW1, emB1, emW2, emB2, vW, vb, out + NB * NA);
    stage1_kernel<TM><<<480 / TM, 256, 0, stream>>>(x,
        crW0, crB0, crW1, crB1, crW2, crB2,
        tmW0, tmB0, tmW1, tmB1, tmW2, tmB2, s1, rews0);
    stage2_kernel<TM><<<7200 / TM, 256, 0, stream>>>(s1,
        crW0, crB0, crW1, crB1, crW2, crB2,
        tmW0, tmB0, tmW1, tmB1, tmW2, tmB2, s2, cont1, rews1);
    k3a_kernel<<<108000 / 32, 256, 0, stream>>>(s2, planes, crW0, crB0, crB1, crW2, crB2, cont2);
    k3b_kernel<<<(108000 + 63) / 64, 256, 0, stream>>>(s2, planes, tmW0,
        tmB0, tmB1, tmB2, emB0, emB1, emB2, vW, vb, Vns3);
    finalize_kernel<<<NB, 256, 0, stream>>>(Vns3, cont2, rews0, rews1, cont1, out);
}

// Round 3
// 785.135 us; speedup vs baseline: 2.5467x; 1.3532x over previous
//
#include <hip/hip_runtime.h>

#define NA 15
#define NB 32
#define DD 256
#define LDA 260   // 257 rounded up to mult of 4 (fp32 stage1/2 kernels)
#define PL 65536  // shorts per weight plane (8 slices x 256 rows x 32 k)

using bf16x8 = __attribute__((ext_vector_type(8))) short;
using f32x4  = __attribute__((ext_vector_type(4))) float;

__device__ __forceinline__ unsigned short f2bf(float f){
  unsigned int u = __float_as_uint(f);
  u = u + 0x7fffu + ((u >> 16) & 1u);
  return (unsigned short)(u >> 16);
}
__device__ __forceinline__ float bf2f(unsigned short h){
  return __uint_as_float(((unsigned int)h) << 16);
}

// ---------------------------------------------------------------------------
// fp32 VALU kernels (unchanged): value(x), stage1, stage2, finalize
// ---------------------------------------------------------------------------
template<int TM, bool RELU>
__device__ __forceinline__ void layer256(
    const float* __restrict__ W, const float* __restrict__ bias,
    const float* act, int K, int lda, float* out, int ldo)
{
    constexpr int RPG = TM / 4;
    const int tid = threadIdx.x;
    const int tr = tid >> 6;
    const int tc = tid & 63;
    float acc[RPG][4];
#pragma unroll
    for (int i = 0; i < RPG; ++i) { acc[i][0]=0.f; acc[i][1]=0.f; acc[i][2]=0.f; acc[i][3]=0.f; }
    const float* wp = W + 4 * tc;
    int k = 0;
    for (; k + 4 <= K; k += 4) {
        float4 w0 = *reinterpret_cast<const float4*>(wp + (k + 0) * DD);
        float4 w1 = *reinterpret_cast<const float4*>(wp + (k + 1) * DD);
        float4 w2 = *reinterpret_cast<const float4*>(wp + (k + 2) * DD);
        float4 w3 = *reinterpret_cast<const float4*>(wp + (k + 3) * DD);
#pragma unroll
        for (int i = 0; i < RPG; ++i) {
            float4 a = *reinterpret_cast<const float4*>(act + (RPG * tr + i) * lda + k);
            acc[i][0] += a.x * w0.x + a.y * w1.x + a.z * w2.x + a.w * w3.x;
            acc[i][1] += a.x * w0.y + a.y * w1.y + a.z * w2.y + a.w * w3.y;
            acc[i][2] += a.x * w0.z + a.y * w1.z + a.z * w2.z + a.w * w3.z;
            acc[i][3] += a.x * w0.w + a.y * w1.w + a.z * w2.w + a.w * w3.w;
        }
    }
    for (; k < K; ++k) {
        float4 w0 = *reinterpret_cast<const float4*>(wp + k * DD);
#pragma unroll
        for (int i = 0; i < RPG; ++i) {
            float a = act[(RPG * tr + i) * lda + k];
            acc[i][0] += a * w0.x; acc[i][1] += a * w0.y;
            acc[i][2] += a * w0.z; acc[i][3] += a * w0.w;
        }
    }
    float4 bb = *reinterpret_cast<const float4*>(bias + 4 * tc);
#pragma unroll
    for (int i = 0; i < RPG; ++i) {
        float4 o;
        o.x = acc[i][0] + bb.x; o.y = acc[i][1] + bb.y;
        o.z = acc[i][2] + bb.z; o.w = acc[i][3] + bb.w;
        if (RELU) {
            o.x = fmaxf(o.x, 0.f); o.y = fmaxf(o.y, 0.f);
            o.z = fmaxf(o.z, 0.f); o.w = fmaxf(o.w, 0.f);
        }
        *reinterpret_cast<float4*>(out + (RPG * tr + i) * ldo + 4 * tc) = o;
    }
}

template<int TM>
__device__ __forceinline__ void head1c(
    const float* h, int ldh, const float* __restrict__ W, int wstr, int col, float bias,
    float* __restrict__ gout, int gbase)
{
    const int wv = threadIdx.x >> 6;
    const int lane = threadIdx.x & 63;
    for (int rr = wv; rr < TM; rr += 4) {
        float p = 0.f;
#pragma unroll
        for (int t = 0; t < 4; ++t) {
            int k = lane + 64 * t;
            p += h[rr * ldh + k] * W[k * wstr + col];
        }
#pragma unroll
        for (int m = 1; m < 64; m <<= 1) p += __shfl_xor(p, m);
        if (lane == 0) gout[gbase + rr] = p + bias;
    }
}

template<int TM>
__device__ __forceinline__ void head2c(
    const float* h, int ldh, const float* __restrict__ W, const float* __restrict__ b2,
    float* __restrict__ g0, float* __restrict__ g1, int gbase)
{
    const int wv = threadIdx.x >> 6;
    const int lane = threadIdx.x & 63;
    for (int rr = wv; rr < TM; rr += 4) {
        float p0 = 0.f, p1 = 0.f;
#pragma unroll
        for (int t = 0; t < 4; ++t) {
            int k = lane + 64 * t;
            float hv = h[rr * ldh + k];
            p0 += hv * W[k * 2 + 0];
            p1 += hv * W[k * 2 + 1];
        }
#pragma unroll
        for (int m = 1; m < 64; m <<= 1) { p0 += __shfl_xor(p0, m); p1 += __shfl_xor(p1, m); }
        if (lane == 0) { g0[gbase + rr] = p0 + b2[0]; g1[gbase + rr] = p1 + b2[1]; }
    }
}

__global__ __launch_bounds__(256) void value_x_kernel(
    const float* __restrict__ x,
    const float* __restrict__ emW0, const float* __restrict__ emB0,
    const float* __restrict__ emW1, const float* __restrict__ emB1,
    const float* __restrict__ emW2, const float* __restrict__ emB2,
    const float* __restrict__ vW, const float* __restrict__ vb,
    float* __restrict__ vout)
{
    constexpr int TM = 32;
    __shared__ __align__(16) float bufA[TM][DD];
    __shared__ __align__(16) float bufB[TM][DD];
    __shared__ __align__(16) float bufC[TM][DD];
    const int tid = threadIdx.x;
    for (int i = 0; i < TM; ++i) bufA[i][tid] = x[i * DD + tid];
    __syncthreads();
    layer256<TM, true >(emW0, emB0, &bufA[0][0], 256, DD, &bufB[0][0], DD); __syncthreads();
    layer256<TM, true >(emW1, emB1, &bufB[0][0], 256, DD, &bufC[0][0], DD); __syncthreads();
    layer256<TM, false>(emW2, emB2, &bufC[0][0], 256, DD, &bufB[0][0], DD); __syncthreads();
    head1c<TM>(&bufB[0][0], DD, vW, 1, 0, vb[0], vout, 0);
}

template<int TM>
__global__ __launch_bounds__(256) void stage1_kernel(
    const float* __restrict__ x,
    const float* __restrict__ crW0, const float* __restrict__ crB0,
    const float* __restrict__ crW1, const float* __restrict__ crB1,
    const float* __restrict__ crW2, const float* __restrict__ crB2,
    const float* __restrict__ tmW0, const float* __restrict__ tmB0,
    const float* __restrict__ tmW1, const float* __restrict__ tmB1,
    const float* __restrict__ tmW2, const float* __restrict__ tmB2,
    float* __restrict__ s1, float* __restrict__ rews0)
{
    __shared__ __align__(16) float bufA[TM][LDA];
    __shared__ __align__(16) float bufB[TM][DD];
    __shared__ __align__(16) float bufC[TM][DD];
    const int tid = threadIdx.x;
    const int row0 = blockIdx.x * TM;
    for (int i = 0; i < TM; ++i) bufA[i][tid] = x[((row0 + i) / 15) * DD + tid];
    if (tid < TM) bufA[tid][DD] = (float)((row0 + tid) % 15);
    __syncthreads();
    layer256<TM, true >(crW0, crB0, &bufA[0][0], 257, LDA, &bufB[0][0], DD); __syncthreads();
    layer256<TM, true >(crW1, crB1, &bufB[0][0], 256, DD, &bufC[0][0], DD); __syncthreads();
    head1c<TM>(&bufC[0][0], DD, crW2, 2, 1, crB2[1], rews0, row0);
    layer256<TM, true >(tmW0, tmB0, &bufA[0][0], 257, LDA, &bufB[0][0], DD); __syncthreads();
    layer256<TM, true >(tmW1, tmB1, &bufB[0][0], 256, DD, &bufC[0][0], DD); __syncthreads();
    layer256<TM, false>(tmW2, tmB2, &bufC[0][0], 256, DD, &bufB[0][0], DD); __syncthreads();
    for (int i = 0; i < TM; ++i) s1[(row0 + i) * DD + tid] = bufB[i][tid];
}

template<int TM>
__global__ __launch_bounds__(256) void stage2_kernel(
    const float* __restrict__ s1,
    const float* __restrict__ crW0, const float* __restrict__ crB0,
    const float* __restrict__ crW1, const float* __restrict__ crB1,
    const float* __restrict__ crW2, const float* __restrict__ crB2,
    const float* __restrict__ tmW0, const float* __restrict__ tmB0,
    const float* __restrict__ tmW1, const float* __restrict__ tmB1,
    const float* __restrict__ tmW2, const float* __restrict__ tmB2,
    float* __restrict__ s2, float* __restrict__ cont1, float* __restrict__ rews1)
{
    __shared__ __align__(16) float bufA[TM][LDA];
    __shared__ __align__(16) float bufB[TM][DD];
    __shared__ __align__(16) float bufC[TM][DD];
    const int tid = threadIdx.x;
    const int row0 = blockIdx.x * TM;
    for (int i = 0; i < TM; ++i) bufA[i][tid] = s1[((row0 + i) / 15) * DD + tid];
    if (tid < TM) bufA[tid][DD] = (float)((row0 + tid) % 15);
    __syncthreads();
    layer256<TM, true >(crW0, crB0, &bufA[0][0], 257, LDA, &bufB[0][0], DD); __syncthreads();
    layer256<TM, true >(crW1, crB1, &bufB[0][0], 256, DD, &bufC[0][0], DD); __syncthreads();
    head2c<TM>(&bufC[0][0], DD, crW2, crB2, cont1, rews1, row0);
    layer256<TM, true >(tmW0, tmB0, &bufA[0][0], 257, LDA, &bufB[0][0], DD); __syncthreads();
    layer256<TM, true >(tmW1, tmB1, &bufB[0][0], 256, DD, &bufC[0][0], DD); __syncthreads();
    layer256<TM, false>(tmW2, tmB2, &bufC[0][0], 256, DD, &bufB[0][0], DD); __syncthreads();
    for (int i = 0; i < TM; ++i) {
        int r = row0 + i;
        int b = r / 225, a1 = (r / 15) % 15, a2 = r % 15;
        s2[((b * 15 + a2) * 15 + a1) * DD + tid] = bufB[i][tid];
    }
}

__global__ __launch_bounds__(256) void finalize_kernel(
    const float* __restrict__ Vns3, const float* __restrict__ cont2,
    const float* __restrict__ rews0, const float* __restrict__ rews1,
    const float* __restrict__ cont1, float* __restrict__ out)
{
    const int b = blockIdx.x;
    const int tid = threadIdx.x;
    __shared__ float vs2[NA][NA];
    __shared__ float vs3[NA];
    if (tid < NA * NA) {
        const int x = tid / NA, y = tid % NA;
        float vals[NA];
        float m = -INFINITY;
#pragma unroll
        for (int z = 0; z < NA; ++z) {
            int vidx = ((b * NA + y) * NA + z) * NA + x;
            int cidx = ((b * NA + x) * NA + y) * NA + z;
            float c1 = rews0[b * NA + z] * 0.99f;
            float c2 = (c1 + rews1[(b * NA + x) * NA + z]) * 0.99f;
            float v = Vns3[vidx] * 0.970299f + c2;
            if (cont2[cidx] > 0.f) v = 0.f;
            vals[z] = v;
            m = fmaxf(m, v);
        }
        float se = 0.f, sw = 0.f;
#pragma unroll
        for (int z = 0; z < NA; ++z) { float e = expf(vals[z] - m); se += e; sw += e * vals[z]; }
        vs2[x][y] = sw / se;
    }
    __syncthreads();
    if (tid < NA) {
        const int x = tid;
        float vals[NA];
        float m = -INFINITY;
#pragma unroll
        for (int y = 0; y < NA; ++y) {
            float v = vs2[x][y];
            if (cont1[(b * NA + x) * NA + y] > 0.f) v = 0.f;
            vals[y] = v;
            m = fmaxf(m, v);
        }
        float se = 0.f, sw = 0.f;
#pragma unroll
        for (int y = 0; y < NA; ++y) { float e = expf(vals[y] - m); se += e; sw += e * vals[y]; }
        vs3[x] = sw / se;
    }
    __syncthreads();
    if (tid == 0) {
        float m = -INFINITY;
#pragma unroll
        for (int x = 0; x < NA; ++x) m = fmaxf(m, vs3[x]);
        float se = 0.f;
#pragma unroll
        for (int x = 0; x < NA; ++x) se += expf(vs3[x] - m);
        float l = logf(se);
#pragma unroll
        for (int x = 0; x < NA; ++x) out[b * NA + x] = vs3[x] - m - l;
    }
}

// ---------------------------------------------------------------------------
// prep: transpose + bf16-split weights into fragment-linear planes (unchanged).
// planes 0-2: crW0 h/m/l; 3-5: crW1 h/m/l; 6,7: tmW0 h/l; 8,9: tmW1; 10,11: tmW2;
// 12,13: emW0; 14,15: emW1; 16,17: emW2.
// ---------------------------------------------------------------------------
__global__ __launch_bounds__(256) void prep_kernel(
    const float* __restrict__ crW0, const float* __restrict__ crW1,
    const float* __restrict__ tmW0, const float* __restrict__ tmW1,
    const float* __restrict__ tmW2, const float* __restrict__ emW0,
    const float* __restrict__ emW1, const float* __restrict__ emW2,
    short* __restrict__ planes)
{
    const int mat = blockIdx.x >> 3;
    const int kk  = blockIdx.x & 7;
    const float* W; int pbase; int ns;
    switch (mat) {
        case 0: W = crW0; pbase = 0;  ns = 3; break;
        case 1: W = crW1; pbase = 3;  ns = 3; break;
        case 2: W = tmW0; pbase = 6;  ns = 2; break;
        case 3: W = tmW1; pbase = 8;  ns = 2; break;
        case 4: W = tmW2; pbase = 10; ns = 2; break;
        case 5: W = emW0; pbase = 12; ns = 2; break;
        case 6: W = emW1; pbase = 14; ns = 2; break;
        default: W = emW2; pbase = 16; ns = 2; break;
    }
    const int col = threadIdx.x;
    short bh[32], bm[32], bl[32];
#pragma unroll
    for (int j = 0; j < 32; ++j) {
        float w = W[(kk * 32 + j) * 256 + col];
        unsigned short h = f2bf(w); float fh = bf2f(h);
        float r1 = w - fh;
        if (ns == 3) {
            unsigned short m = f2bf(r1); float fm = bf2f(m);
            bm[j] = (short)m; bl[j] = (short)f2bf(r1 - fm);
        } else {
            bm[j] = 0; bl[j] = (short)f2bf(r1);
        }
        bh[j] = (short)h;
    }
    short* pH = planes + (size_t)pbase * PL + kk * 8192 + col * 32;
#pragma unroll
    for (int j = 0; j < 32; j += 4) *(short4*)(pH + j) = make_short4(bh[j], bh[j+1], bh[j+2], bh[j+3]);
    short* pN = planes + (size_t)(pbase + 1) * PL + kk * 8192 + col * 32;
    const short* s1p = (ns == 3) ? bm : bl;
#pragma unroll
    for (int j = 0; j < 32; j += 4) *(short4*)(pN + j) = make_short4(s1p[j], s1p[j+1], s1p[j+2], s1p[j+3]);
    if (ns == 3) {
        short* pL = planes + (size_t)(pbase + 2) * PL + kk * 8192 + col * 32;
#pragma unroll
        for (int j = 0; j < 32; j += 4) *(short4*)(pL + j) = make_short4(bl[j], bl[j+1], bl[j+2], bl[j+3]);
    }
}

// ---------------------------------------------------------------------------
// MFMA stage-3: weights loaded straight into VGPR fragments from the
// fragment-linear planes (coalesced, L2-resident). No weight LDS, no per-kk
// barriers, no vmcnt drains. Act stays in LDS (stride 264: conflict-free).
// ---------------------------------------------------------------------------

// 2-way split, 3 MFMA passes; 64 rows per block.
template<bool RELU, bool RANK1, bool HEAD, bool WRITEACT>
__device__ __forceinline__ void layer_g2(
    const short* __restrict__ plH, const short* __restrict__ plL,
    const float* __restrict__ bias, const float* __restrict__ w0r256,
    const float* __restrict__ headW, const float* __restrict__ headB,
    float* __restrict__ headOut, int row0,
    short* actH, short* actL, float* hred)
{
    const int tid = threadIdx.x;
    const int ln15 = tid & 15, lng = (tid >> 4) & 3, wv = tid >> 6;
    const int wo = (wv * 64 + ln15) * 32 + lng * 8;   // + ct*512 + kk*8192
    f32x4 acc[4][4];
#pragma unroll
    for (int a = 0; a < 4; ++a)
#pragma unroll
        for (int b = 0; b < 4; ++b) acc[a][b] = f32x4{0.f, 0.f, 0.f, 0.f};

    bf16x8 aH[2][4], aL[2][4];
#pragma unroll
    for (int ct = 0; ct < 4; ++ct) {
        aH[0][ct] = *(const bf16x8*)(plH + wo + ct * 512);
        aL[0][ct] = *(const bf16x8*)(plL + wo + ct * 512);
    }
#pragma unroll
    for (int kk = 0; kk < 8; ++kk) {
        if (kk < 7) {
#pragma unroll
            for (int ct = 0; ct < 4; ++ct) {
                aH[(kk + 1) & 1][ct] = *(const bf16x8*)(plH + wo + (kk + 1) * 8192 + ct * 512);
                aL[(kk + 1) & 1][ct] = *(const bf16x8*)(plL + wo + (kk + 1) * 8192 + ct * 512);
            }
        }
        bf16x8 bH[4], bL[4];
#pragma unroll
        for (int rt = 0; rt < 4; ++rt) {
            int off = (rt * 16 + ln15) * 264 + kk * 32 + lng * 8;
            bH[rt] = *(const bf16x8*)(actH + off);
            bL[rt] = *(const bf16x8*)(actL + off);
        }
#pragma unroll
        for (int ct = 0; ct < 4; ++ct)
#pragma unroll
            for (int rt = 0; rt < 4; ++rt) {
                acc[ct][rt] = __builtin_amdgcn_mfma_f32_16x16x32_bf16(aH[kk & 1][ct], bH[rt], acc[ct][rt], 0, 0, 0);
                acc[ct][rt] = __builtin_amdgcn_mfma_f32_16x16x32_bf16(aH[kk & 1][ct], bL[rt], acc[ct][rt], 0, 0, 0);
                acc[ct][rt] = __builtin_amdgcn_mfma_f32_16x16x32_bf16(aL[kk & 1][ct], bH[rt], acc[ct][rt], 0, 0, 0);
            }
    }
    __syncthreads();   // all act reads done before in-place overwrite

    float hp[4] = {0.f, 0.f, 0.f, 0.f};
#pragma unroll
    for (int ct = 0; ct < 4; ++ct) {
        const int colb = wv * 64 + ct * 16 + lng * 4;
        const float4 bb = *(const float4*)(bias + colb);
        float4 wr;
        if (RANK1) wr = *(const float4*)(w0r256 + colb);
#pragma unroll
        for (int rt = 0; rt < 4; ++rt) {
            f32x4 v = acc[ct][rt];
            if (RANK1) {
                float a = (float)((row0 + rt * 16 + ln15) % 15);
                v[0] += a * wr.x; v[1] += a * wr.y; v[2] += a * wr.z; v[3] += a * wr.w;
            }
            v[0] += bb.x; v[1] += bb.y; v[2] += bb.z; v[3] += bb.w;
            if (RELU) {
#pragma unroll
                for (int j = 0; j < 4; ++j) v[j] = fmaxf(v[j], 0.f);
            }
            if (HEAD) {
#pragma unroll
                for (int j = 0; j < 4; ++j) hp[rt] += v[j] * headW[colb + j];
            }
            if (WRITEACT) {
                unsigned short hs[4], ls[4];
#pragma unroll
                for (int j = 0; j < 4; ++j) {
                    unsigned short h = f2bf(v[j]); float fh = bf2f(h);
                    hs[j] = h; ls[j] = f2bf(v[j] - fh);
                }
                const int ao = (rt * 16 + ln15) * 264 + colb;
                *(short4*)(actH + ao) = make_short4(hs[0], hs[1], hs[2], hs[3]);
                *(short4*)(actL + ao) = make_short4(ls[0], ls[1], ls[2], ls[3]);
            }
        }
    }
    if constexpr (HEAD) {
#pragma unroll
        for (int rt = 0; rt < 4; ++rt) {
            hp[rt] += __shfl_xor(hp[rt], 16);
            hp[rt] += __shfl_xor(hp[rt], 32);
        }
        if (lng == 0) {
#pragma unroll
            for (int rt = 0; rt < 4; ++rt) hred[wv * 64 + rt * 16 + ln15] = hp[rt];
        }
        __syncthreads();
        if (tid < 64) {
            float s = hred[tid] + hred[64 + tid] + hred[128 + tid] + hred[192 + tid] + headB[0];
            int r = row0 + tid;
            if (r < 108000) headOut[r] = s;
        }
    }
    if constexpr (WRITEACT) __syncthreads();
}

// 3-way split, 6 MFMA passes; 32 rows per block (mask-grade precision).
template<bool RANK1, bool HEAD, bool WRITEACT>
__device__ __forceinline__ void layer_g3(
    const short* __restrict__ plH, const short* __restrict__ plM, const short* __restrict__ plL,
    const float* __restrict__ bias, const float* __restrict__ w0r256,
    const float* __restrict__ headW, int headStride, const float* __restrict__ headB,
    float* __restrict__ headOut, int row0,
    short* actH, short* actM, short* actL, float* hred)
{
    const int tid = threadIdx.x;
    const int ln15 = tid & 15, lng = (tid >> 4) & 3, wv = tid >> 6;
    const int wo = (wv * 64 + ln15) * 32 + lng * 8;
    f32x4 acc[4][2];
#pragma unroll
    for (int a = 0; a < 4; ++a) { acc[a][0] = f32x4{0.f,0.f,0.f,0.f}; acc[a][1] = f32x4{0.f,0.f,0.f,0.f}; }

#pragma unroll
    for (int kk = 0; kk < 8; ++kk) {
        bf16x8 wH[4], wM[4], wL[4], xH[2], xM[2], xL[2];
#pragma unroll
        for (int ct = 0; ct < 4; ++ct) {
            wH[ct] = *(const bf16x8*)(plH + wo + kk * 8192 + ct * 512);
            wM[ct] = *(const bf16x8*)(plM + wo + kk * 8192 + ct * 512);
            wL[ct] = *(const bf16x8*)(plL + wo + kk * 8192 + ct * 512);
        }
#pragma unroll
        for (int rt = 0; rt < 2; ++rt) {
            int off = (rt * 16 + ln15) * 264 + kk * 32 + lng * 8;
            xH[rt] = *(const bf16x8*)(actH + off);
            xM[rt] = *(const bf16x8*)(actM + off);
            xL[rt] = *(const bf16x8*)(actL + off);
        }
#pragma unroll
        for (int ct = 0; ct < 4; ++ct)
#pragma unroll
            for (int rt = 0; rt < 2; ++rt) {
                acc[ct][rt] = __builtin_amdgcn_mfma_f32_16x16x32_bf16(wH[ct], xH[rt], acc[ct][rt], 0, 0, 0);
                acc[ct][rt] = __builtin_amdgcn_mfma_f32_16x16x32_bf16(wH[ct], xM[rt], acc[ct][rt], 0, 0, 0);
                acc[ct][rt] = __builtin_amdgcn_mfma_f32_16x16x32_bf16(wM[ct], xH[rt], acc[ct][rt], 0, 0, 0);
                acc[ct][rt] = __builtin_amdgcn_mfma_f32_16x16x32_bf16(wM[ct], xM[rt], acc[ct][rt], 0, 0, 0);
                acc[ct][rt] = __builtin_amdgcn_mfma_f32_16x16x32_bf16(wH[ct], xL[rt], acc[ct][rt], 0, 0, 0);
                acc[ct][rt] = __builtin_amdgcn_mfma_f32_16x16x32_bf16(wL[ct], xH[rt], acc[ct][rt], 0, 0, 0);
            }
    }
    __syncthreads();

    float hp[2] = {0.f, 0.f};
#pragma unroll
    for (int ct = 0; ct < 4; ++ct) {
        const int colb = wv * 64 + ct * 16 + lng * 4;
        const float4 bb = *(const float4*)(bias + colb);
        float4 wr;
        if (RANK1) wr = *(const float4*)(w0r256 + colb);
#pragma unroll
        for (int rt = 0; rt < 2; ++rt) {
            f32x4 v = acc[ct][rt];
            if (RANK1) {
                float a = (float)((row0 + rt * 16 + ln15) % 15);
                v[0] += a * wr.x; v[1] += a * wr.y; v[2] += a * wr.z; v[3] += a * wr.w;
            }
            v[0] += bb.x; v[1] += bb.y; v[2] += bb.z; v[3] += bb.w;
#pragma unroll
            for (int j = 0; j < 4; ++j) v[j] = fmaxf(v[j], 0.f);   // both cr layers are relu
            if (HEAD) {
#pragma unroll
                for (int j = 0; j < 4; ++j) hp[rt] += v[j] * headW[(colb + j) * headStride];
            }
            if (WRITEACT) {
                unsigned short hs[4], ms[4], ls[4];
#pragma unroll
                for (int j = 0; j < 4; ++j) {
                    unsigned short h = f2bf(v[j]); float fh = bf2f(h);
                    float r1 = v[j] - fh;
                    unsigned short m = f2bf(r1); float fm = bf2f(m);
                    hs[j] = h; ms[j] = m; ls[j] = f2bf(r1 - fm);
                }
                const int ao = (rt * 16 + ln15) * 264 + colb;
                *(short4*)(actH + ao) = make_short4(hs[0], hs[1], hs[2], hs[3]);
                *(short4*)(actM + ao) = make_short4(ms[0], ms[1], ms[2], ms[3]);
                *(short4*)(actL + ao) = make_short4(ls[0], ls[1], ls[2], ls[3]);
            }
        }
    }
    if constexpr (HEAD) {
#pragma unroll
        for (int rt = 0; rt < 2; ++rt) {
            hp[rt] += __shfl_xor(hp[rt], 16);
            hp[rt] += __shfl_xor(hp[rt], 32);
        }
        if (lng == 0) {
#pragma unroll
            for (int rt = 0; rt < 2; ++rt) hred[wv * 32 + rt * 16 + ln15] = hp[rt];
        }
        __syncthreads();
        if (tid < 32) {
            float s = hred[tid] + hred[32 + tid] + hred[64 + tid] + hred[96 + tid] + headB[0];
            int r = row0 + tid;
            if (r < 108000) headOut[r] = s;
        }
    }
    if constexpr (WRITEACT) __syncthreads();
}

__global__ __launch_bounds__(256, 2) void k3b_kernel(
    const float* __restrict__ s2, const short* __restrict__ planes,
    const float* __restrict__ tmW0,
    const float* __restrict__ tmB0, const float* __restrict__ tmB1, const float* __restrict__ tmB2,
    const float* __restrict__ emB0, const float* __restrict__ emB1, const float* __restrict__ emB2,
    const float* __restrict__ vW, const float* __restrict__ vb,
    float* __restrict__ Vns3)
{
    __shared__ short actH[64 * 264];
    __shared__ short actL[64 * 264];
    __shared__ float hred[256];
    const int tid = threadIdx.x;
    const int row0 = blockIdx.x * 64;
    const int wv = tid >> 6, ln = tid & 63;
    for (int i = wv * 16; i < wv * 16 + 16; ++i) {
        int srow = (row0 + i) / 15; if (srow > 7199) srow = 7199;
        float4 s = *(const float4*)(s2 + srow * 256 + ln * 4);
        unsigned short hs[4], ls[4];
        float sv[4] = {s.x, s.y, s.z, s.w};
#pragma unroll
        for (int j = 0; j < 4; ++j) {
            unsigned short h = f2bf(sv[j]); float fh = bf2f(h);
            hs[j] = h; ls[j] = f2bf(sv[j] - fh);
        }
        *(short4*)(actH + i * 264 + ln * 4) = make_short4(hs[0], hs[1], hs[2], hs[3]);
        *(short4*)(actL + i * 264 + ln * 4) = make_short4(ls[0], ls[1], ls[2], ls[3]);
    }
    __syncthreads();
    const short* P = planes;
    layer_g2<true,  true,  false, true >(P + 6 * PL,  P + 7 * PL,  tmB0, tmW0 + 65536,
                                         nullptr, nullptr, nullptr, row0, actH, actL, hred);
    layer_g2<true,  false, false, true >(P + 8 * PL,  P + 9 * PL,  tmB1, nullptr,
                                         nullptr, nullptr, nullptr, row0, actH, actL, hred);
    layer_g2<false, false, false, true >(P + 10 * PL, P + 11 * PL, tmB2, nullptr,
                                         nullptr, nullptr, nullptr, row0, actH, actL, hred);
    layer_g2<true,  false, false, true >(P + 12 * PL, P + 13 * PL, emB0, nullptr,
                                         nullptr, nullptr, nullptr, row0, actH, actL, hred);
    layer_g2<true,  false, false, true >(P + 14 * PL, P + 15 * PL, emB1, nullptr,
                                         nullptr, nullptr, nullptr, row0, actH, actL, hred);
    layer_g2<false, false, true,  false>(P + 16 * PL, P + 17 * PL, emB2, nullptr,
                                         vW, vb, Vns3, row0, actH, actL, hred);
}

__global__ __launch_bounds__(256, 2) void k3a_kernel(
    const float* __restrict__ s2, const short* __restrict__ planes,
    const float* __restrict__ crW0, const float* __restrict__ crB0,
    const float* __restrict__ crB1, const float* __restrict__ crW2,
    const float* __restrict__ crB2, float* __restrict__ cont2)
{
    __shared__ short actH[32 * 264];
    __shared__ short actM[32 * 264];
    __shared__ short actL[32 * 264];
    __shared__ float hred[128];
    const int tid = threadIdx.x;
    const int row0 = blockIdx.x * 32;
    const int wv = tid >> 6, ln = tid & 63;
    for (int i = wv * 8; i < wv * 8 + 8; ++i) {
        int srow = (row0 + i) / 15; if (srow > 7199) srow = 7199;
        float4 s = *(const float4*)(s2 + srow * 256 + ln * 4);
        unsigned short hs[4], ms[4], ls[4];
        float sv[4] = {s.x, s.y, s.z, s.w};
#pragma unroll
        for (int j = 0; j < 4; ++j) {
            unsigned short h = f2bf(sv[j]); float fh = bf2f(h);
            float r1 = sv[j] - fh;
            unsigned short m = f2bf(r1); float fm = bf2f(m);
            hs[j] = h; ms[j] = m; ls[j] = f2bf(r1 - fm);
        }
        *(short4*)(actH + i * 264 + ln * 4) = make_short4(hs[0], hs[1], hs[2], hs[3]);
        *(short4*)(actM + i * 264 + ln * 4) = make_short4(ms[0], ms[1], ms[2], ms[3]);
        *(short4*)(actL + i * 264 + ln * 4) = make_short4(ls[0], ls[1], ls[2], ls[3]);
    }
    __syncthreads();
    const short* P = planes;
    layer_g3<true,  false, true >(P + 0 * PL, P + 1 * PL, P + 2 * PL, crB0, crW0 + 65536,
                                  nullptr, 0, nullptr, nullptr, row0, actH, actM, actL, hred);
    layer_g3<false, true,  false>(P + 3 * PL, P + 4 * PL, P + 5 * PL, crB1, nullptr,
                                  crW2, 2, crB2, cont2, row0, actH, actM, actL, hred);
}

extern "C" void kernel_launch(void* const* d_in, const int* in_sizes, int n_in,
                              void* d_out, int out_size, void* d_ws, size_t ws_size,
                              hipStream_t stream)
{
    (void)in_sizes; (void)n_in; (void)out_size; (void)ws_size;
    const float* x    = (const float*)d_in[0];
    const float* emW0 = (const float*)d_in[1];
    const float* emB0 = (const float*)d_in[2];
    const float* emW1 = (const float*)d_in[3];
    const float* emB1 = (const float*)d_in[4];
    const float* emW2 = (const float*)d_in[5];
    const float* emB2 = (const float*)d_in[6];
    const float* vW   = (const float*)d_in[7];
    const float* vb   = (const float*)d_in[8];
    const float* crW0 = (const float*)d_in[9];
    const float* crB0 = (const float*)d_in[10];
    const float* crW1 = (const float*)d_in[11];
    const float* crB1 = (const float*)d_in[12];
    const float* crW2 = (const float*)d_in[13];
    const float* crB2 = (const float*)d_in[14];
    const float* tmW0 = (const float*)d_in[15];
    const float* tmB0 = (const float*)d_in[16];
    const float* tmW1 = (const float*)d_in[17];
    const float* tmB1 = (const float*)d_in[18];
    const float* tmW2 = (const float*)d_in[19];
    const float* tmB2 = (const float*)d_in[20];
    float* out = (float*)d_out;

    float* w     = (float*)d_ws;
    float* rews0 = w;                     // 480
    float* cont1 = rews0 + 480;           // 7200
    float* rews1 = cont1 + 7200;          // 7200
    float* cont2 = rews1 + 7200;          // 108000
    float* Vns3  = cont2 + 108000;        // 108000
    float* s1    = Vns3 + 108000;         // 480*256
    float* s2    = s1 + 480 * 256;        // 7200*256
    short* planes = (short*)(s2 + 7200 * 256);  // 18 * 65536 shorts = 2.25 MB

    constexpr int TM = 24;
    prep_kernel<<<64, 256, 0, stream>>>(crW0, crW1, tmW0, tmW1, tmW2, emW0, emW1, emW2, planes);
    value_x_kernel<<<1, 256, 0, stream>>>(x, emW0, emB0, emW1, emB1, emW2, emB2, vW, vb, out + NB * NA);
    stage1_kernel<TM><<<480 / TM, 256, 0, stream>>>(x,
        crW0, crB0, crW1, crB1, crW2, crB2,
        tmW0, tmB0, tmW1, tmB1, tmW2, tmB2, s1, rews0);
    stage2_kernel<TM><<<7200 / TM, 256, 0, stream>>>(s1,
        crW0, crB0, crW1, crB1, crW2, crB2,
        tmW0, tmB0, tmW1, tmB1, tmW2, tmB2, s2, cont1, rews1);
    k3a_kernel<<<108000 / 32, 256, 0, stream>>>(s2, planes, crW0, crB0, crB1, crW2, crB2, cont2);
    k3b_kernel<<<(108000 + 63) / 64, 256, 0, stream>>>(s2, planes, tmW0,
        tmB0, tmB1, tmB2, emB0, emB1, emB2, vW, vb, Vns3);
    finalize_kernel<<<NB, 256, 0, stream>>>(Vns3, cont2, rews0, rews1, cont1, out);
}

// Round 4
// 674.285 us; speedup vs baseline: 2.9654x; 1.1644x over previous
//
#include <hip/hip_runtime.h>

#define NA 15
#define NB 32
#define DD 256
#define LDA 260   // 257 rounded up to mult of 4 (fp32 stage1/2 kernels)
#define PL 65536  // shorts per weight plane (8 slices x 256 rows x 32 k)

using bf16x8 = __attribute__((ext_vector_type(8))) short;
using f32x4  = __attribute__((ext_vector_type(4))) float;

__device__ __forceinline__ unsigned short f2bf(float f){
  unsigned int u = __float_as_uint(f);
  u = u + 0x7fffu + ((u >> 16) & 1u);
  return (unsigned short)(u >> 16);
}
__device__ __forceinline__ float bf2f(unsigned short h){
  return __uint_as_float(((unsigned int)h) << 16);
}

// ---------------------------------------------------------------------------
// fp32 VALU kernels (unchanged): value(x), stage1, stage2, finalize
// ---------------------------------------------------------------------------
template<int TM, bool RELU>
__device__ __forceinline__ void layer256(
    const float* __restrict__ W, const float* __restrict__ bias,
    const float* act, int K, int lda, float* out, int ldo)
{
    constexpr int RPG = TM / 4;
    const int tid = threadIdx.x;
    const int tr = tid >> 6;
    const int tc = tid & 63;
    float acc[RPG][4];
#pragma unroll
    for (int i = 0; i < RPG; ++i) { acc[i][0]=0.f; acc[i][1]=0.f; acc[i][2]=0.f; acc[i][3]=0.f; }
    const float* wp = W + 4 * tc;
    int k = 0;
    for (; k + 4 <= K; k += 4) {
        float4 w0 = *reinterpret_cast<const float4*>(wp + (k + 0) * DD);
        float4 w1 = *reinterpret_cast<const float4*>(wp + (k + 1) * DD);
        float4 w2 = *reinterpret_cast<const float4*>(wp + (k + 2) * DD);
        float4 w3 = *reinterpret_cast<const float4*>(wp + (k + 3) * DD);
#pragma unroll
        for (int i = 0; i < RPG; ++i) {
            float4 a = *reinterpret_cast<const float4*>(act + (RPG * tr + i) * lda + k);
            acc[i][0] += a.x * w0.x + a.y * w1.x + a.z * w2.x + a.w * w3.x;
            acc[i][1] += a.x * w0.y + a.y * w1.y + a.z * w2.y + a.w * w3.y;
            acc[i][2] += a.x * w0.z + a.y * w1.z + a.z * w2.z + a.w * w3.z;
            acc[i][3] += a.x * w0.w + a.y * w1.w + a.z * w2.w + a.w * w3.w;
        }
    }
    for (; k < K; ++k) {
        float4 w0 = *reinterpret_cast<const float4*>(wp + k * DD);
#pragma unroll
        for (int i = 0; i < RPG; ++i) {
            float a = act[(RPG * tr + i) * lda + k];
            acc[i][0] += a * w0.x; acc[i][1] += a * w0.y;
            acc[i][2] += a * w0.z; acc[i][3] += a * w0.w;
        }
    }
    float4 bb = *reinterpret_cast<const float4*>(bias + 4 * tc);
#pragma unroll
    for (int i = 0; i < RPG; ++i) {
        float4 o;
        o.x = acc[i][0] + bb.x; o.y = acc[i][1] + bb.y;
        o.z = acc[i][2] + bb.z; o.w = acc[i][3] + bb.w;
        if (RELU) {
            o.x = fmaxf(o.x, 0.f); o.y = fmaxf(o.y, 0.f);
            o.z = fmaxf(o.z, 0.f); o.w = fmaxf(o.w, 0.f);
        }
        *reinterpret_cast<float4*>(out + (RPG * tr + i) * ldo + 4 * tc) = o;
    }
}

template<int TM>
__device__ __forceinline__ void head1c(
    const float* h, int ldh, const float* __restrict__ W, int wstr, int col, float bias,
    float* __restrict__ gout, int gbase)
{
    const int wv = threadIdx.x >> 6;
    const int lane = threadIdx.x & 63;
    for (int rr = wv; rr < TM; rr += 4) {
        float p = 0.f;
#pragma unroll
        for (int t = 0; t < 4; ++t) {
            int k = lane + 64 * t;
            p += h[rr * ldh + k] * W[k * wstr + col];
        }
#pragma unroll
        for (int m = 1; m < 64; m <<= 1) p += __shfl_xor(p, m);
        if (lane == 0) gout[gbase + rr] = p + bias;
    }
}

template<int TM>
__device__ __forceinline__ void head2c(
    const float* h, int ldh, const float* __restrict__ W, const float* __restrict__ b2,
    float* __restrict__ g0, float* __restrict__ g1, int gbase)
{
    const int wv = threadIdx.x >> 6;
    const int lane = threadIdx.x & 63;
    for (int rr = wv; rr < TM; rr += 4) {
        float p0 = 0.f, p1 = 0.f;
#pragma unroll
        for (int t = 0; t < 4; ++t) {
            int k = lane + 64 * t;
            float hv = h[rr * ldh + k];
            p0 += hv * W[k * 2 + 0];
            p1 += hv * W[k * 2 + 1];
        }
#pragma unroll
        for (int m = 1; m < 64; m <<= 1) { p0 += __shfl_xor(p0, m); p1 += __shfl_xor(p1, m); }
        if (lane == 0) { g0[gbase + rr] = p0 + b2[0]; g1[gbase + rr] = p1 + b2[1]; }
    }
}

__global__ __launch_bounds__(256) void value_x_kernel(
    const float* __restrict__ x,
    const float* __restrict__ emW0, const float* __restrict__ emB0,
    const float* __restrict__ emW1, const float* __restrict__ emB1,
    const float* __restrict__ emW2, const float* __restrict__ emB2,
    const float* __restrict__ vW, const float* __restrict__ vb,
    float* __restrict__ vout)
{
    constexpr int TM = 32;
    __shared__ __align__(16) float bufA[TM][DD];
    __shared__ __align__(16) float bufB[TM][DD];
    __shared__ __align__(16) float bufC[TM][DD];
    const int tid = threadIdx.x;
    for (int i = 0; i < TM; ++i) bufA[i][tid] = x[i * DD + tid];
    __syncthreads();
    layer256<TM, true >(emW0, emB0, &bufA[0][0], 256, DD, &bufB[0][0], DD); __syncthreads();
    layer256<TM, true >(emW1, emB1, &bufB[0][0], 256, DD, &bufC[0][0], DD); __syncthreads();
    layer256<TM, false>(emW2, emB2, &bufC[0][0], 256, DD, &bufB[0][0], DD); __syncthreads();
    head1c<TM>(&bufB[0][0], DD, vW, 1, 0, vb[0], vout, 0);
}

template<int TM>
__global__ __launch_bounds__(256) void stage1_kernel(
    const float* __restrict__ x,
    const float* __restrict__ crW0, const float* __restrict__ crB0,
    const float* __restrict__ crW1, const float* __restrict__ crB1,
    const float* __restrict__ crW2, const float* __restrict__ crB2,
    const float* __restrict__ tmW0, const float* __restrict__ tmB0,
    const float* __restrict__ tmW1, const float* __restrict__ tmB1,
    const float* __restrict__ tmW2, const float* __restrict__ tmB2,
    float* __restrict__ s1, float* __restrict__ rews0)
{
    __shared__ __align__(16) float bufA[TM][LDA];
    __shared__ __align__(16) float bufB[TM][DD];
    __shared__ __align__(16) float bufC[TM][DD];
    const int tid = threadIdx.x;
    const int row0 = blockIdx.x * TM;
    for (int i = 0; i < TM; ++i) bufA[i][tid] = x[((row0 + i) / 15) * DD + tid];
    if (tid < TM) bufA[tid][DD] = (float)((row0 + tid) % 15);
    __syncthreads();
    layer256<TM, true >(crW0, crB0, &bufA[0][0], 257, LDA, &bufB[0][0], DD); __syncthreads();
    layer256<TM, true >(crW1, crB1, &bufB[0][0], 256, DD, &bufC[0][0], DD); __syncthreads();
    head1c<TM>(&bufC[0][0], DD, crW2, 2, 1, crB2[1], rews0, row0);
    layer256<TM, true >(tmW0, tmB0, &bufA[0][0], 257, LDA, &bufB[0][0], DD); __syncthreads();
    layer256<TM, true >(tmW1, tmB1, &bufB[0][0], 256, DD, &bufC[0][0], DD); __syncthreads();
    layer256<TM, false>(tmW2, tmB2, &bufC[0][0], 256, DD, &bufB[0][0], DD); __syncthreads();
    for (int i = 0; i < TM; ++i) s1[(row0 + i) * DD + tid] = bufB[i][tid];
}

template<int TM>
__global__ __launch_bounds__(256) void stage2_kernel(
    const float* __restrict__ s1,
    const float* __restrict__ crW0, const float* __restrict__ crB0,
    const float* __restrict__ crW1, const float* __restrict__ crB1,
    const float* __restrict__ crW2, const float* __restrict__ crB2,
    const float* __restrict__ tmW0, const float* __restrict__ tmB0,
    const float* __restrict__ tmW1, const float* __restrict__ tmB1,
    const float* __restrict__ tmW2, const float* __restrict__ tmB2,
    float* __restrict__ s2, float* __restrict__ cont1, float* __restrict__ rews1)
{
    __shared__ __align__(16) float bufA[TM][LDA];
    __shared__ __align__(16) float bufB[TM][DD];
    __shared__ __align__(16) float bufC[TM][DD];
    const int tid = threadIdx.x;
    const int row0 = blockIdx.x * TM;
    for (int i = 0; i < TM; ++i) bufA[i][tid] = s1[((row0 + i) / 15) * DD + tid];
    if (tid < TM) bufA[tid][DD] = (float)((row0 + tid) % 15);
    __syncthreads();
    layer256<TM, true >(crW0, crB0, &bufA[0][0], 257, LDA, &bufB[0][0], DD); __syncthreads();
    layer256<TM, true >(crW1, crB1, &bufB[0][0], 256, DD, &bufC[0][0], DD); __syncthreads();
    head2c<TM>(&bufC[0][0], DD, crW2, crB2, cont1, rews1, row0);
    layer256<TM, true >(tmW0, tmB0, &bufA[0][0], 257, LDA, &bufB[0][0], DD); __syncthreads();
    layer256<TM, true >(tmW1, tmB1, &bufB[0][0], 256, DD, &bufC[0][0], DD); __syncthreads();
    layer256<TM, false>(tmW2, tmB2, &bufC[0][0], 256, DD, &bufB[0][0], DD); __syncthreads();
    for (int i = 0; i < TM; ++i) {
        int r = row0 + i;
        int b = r / 225, a1 = (r / 15) % 15, a2 = r % 15;
        s2[((b * 15 + a2) * 15 + a1) * DD + tid] = bufB[i][tid];
    }
}

__global__ __launch_bounds__(256) void finalize_kernel(
    const float* __restrict__ Vns3, const float* __restrict__ cont2,
    const float* __restrict__ rews0, const float* __restrict__ rews1,
    const float* __restrict__ cont1, float* __restrict__ out)
{
    const int b = blockIdx.x;
    const int tid = threadIdx.x;
    __shared__ float vs2[NA][NA];
    __shared__ float vs3[NA];
    if (tid < NA * NA) {
        const int x = tid / NA, y = tid % NA;
        float vals[NA];
        float m = -INFINITY;
#pragma unroll
        for (int z = 0; z < NA; ++z) {
            int vidx = ((b * NA + y) * NA + z) * NA + x;
            int cidx = ((b * NA + x) * NA + y) * NA + z;
            float c1 = rews0[b * NA + z] * 0.99f;
            float c2 = (c1 + rews1[(b * NA + x) * NA + z]) * 0.99f;
            float v = Vns3[vidx] * 0.970299f + c2;
            if (cont2[cidx] > 0.f) v = 0.f;
            vals[z] = v;
            m = fmaxf(m, v);
        }
        float se = 0.f, sw = 0.f;
#pragma unroll
        for (int z = 0; z < NA; ++z) { float e = expf(vals[z] - m); se += e; sw += e * vals[z]; }
        vs2[x][y] = sw / se;
    }
    __syncthreads();
    if (tid < NA) {
        const int x = tid;
        float vals[NA];
        float m = -INFINITY;
#pragma unroll
        for (int y = 0; y < NA; ++y) {
            float v = vs2[x][y];
            if (cont1[(b * NA + x) * NA + y] > 0.f) v = 0.f;
            vals[y] = v;
            m = fmaxf(m, v);
        }
        float se = 0.f, sw = 0.f;
#pragma unroll
        for (int y = 0; y < NA; ++y) { float e = expf(vals[y] - m); se += e; sw += e * vals[y]; }
        vs3[x] = sw / se;
    }
    __syncthreads();
    if (tid == 0) {
        float m = -INFINITY;
#pragma unroll
        for (int x = 0; x < NA; ++x) m = fmaxf(m, vs3[x]);
        float se = 0.f;
#pragma unroll
        for (int x = 0; x < NA; ++x) se += expf(vs3[x] - m);
        float l = logf(se);
#pragma unroll
        for (int x = 0; x < NA; ++x) out[b * NA + x] = vs3[x] - m - l;
    }
}

// ---------------------------------------------------------------------------
// prep: transpose + bf16-split weights into fragment-linear planes (unchanged).
// planes 0-2: crW0 h/m/l; 3-5: crW1 h/m/l; 6,7: tmW0 h/l; 8,9: tmW1; 10,11: tmW2;
// 12,13: emW0; 14,15: emW1; 16,17: emW2.
// ---------------------------------------------------------------------------
__global__ __launch_bounds__(256) void prep_kernel(
    const float* __restrict__ crW0, const float* __restrict__ crW1,
    const float* __restrict__ tmW0, const float* __restrict__ tmW1,
    const float* __restrict__ tmW2, const float* __restrict__ emW0,
    const float* __restrict__ emW1, const float* __restrict__ emW2,
    short* __restrict__ planes)
{
    const int mat = blockIdx.x >> 3;
    const int kk  = blockIdx.x & 7;
    const float* W; int pbase; int ns;
    switch (mat) {
        case 0: W = crW0; pbase = 0;  ns = 3; break;
        case 1: W = crW1; pbase = 3;  ns = 3; break;
        case 2: W = tmW0; pbase = 6;  ns = 2; break;
        case 3: W = tmW1; pbase = 8;  ns = 2; break;
        case 4: W = tmW2; pbase = 10; ns = 2; break;
        case 5: W = emW0; pbase = 12; ns = 2; break;
        case 6: W = emW1; pbase = 14; ns = 2; break;
        default: W = emW2; pbase = 16; ns = 2; break;
    }
    const int col = threadIdx.x;
    short bh[32], bm[32], bl[32];
#pragma unroll
    for (int j = 0; j < 32; ++j) {
        float w = W[(kk * 32 + j) * 256 + col];
        unsigned short h = f2bf(w); float fh = bf2f(h);
        float r1 = w - fh;
        if (ns == 3) {
            unsigned short m = f2bf(r1); float fm = bf2f(m);
            bm[j] = (short)m; bl[j] = (short)f2bf(r1 - fm);
        } else {
            bm[j] = 0; bl[j] = (short)f2bf(r1);
        }
        bh[j] = (short)h;
    }
    short* pH = planes + (size_t)pbase * PL + kk * 8192 + col * 32;
#pragma unroll
    for (int j = 0; j < 32; j += 4) *(short4*)(pH + j) = make_short4(bh[j], bh[j+1], bh[j+2], bh[j+3]);
    short* pN = planes + (size_t)(pbase + 1) * PL + kk * 8192 + col * 32;
    const short* s1p = (ns == 3) ? bm : bl;
#pragma unroll
    for (int j = 0; j < 32; j += 4) *(short4*)(pN + j) = make_short4(s1p[j], s1p[j+1], s1p[j+2], s1p[j+3]);
    if (ns == 3) {
        short* pL = planes + (size_t)(pbase + 2) * PL + kk * 8192 + col * 32;
#pragma unroll
        for (int j = 0; j < 32; j += 4) *(short4*)(pL + j) = make_short4(bl[j], bl[j+1], bl[j+2], bl[j+3]);
    }
}

// ---------------------------------------------------------------------------
// u_kernel: U_cr = s2 @ crW0[0:256,:] (3-way grade) and U_tm = s2 @ tmW0[0:256,:]
// (2-way grade) on the 7200 distinct s2 rows. fp32 out. The action's rank-1
// contribution + bias + relu are applied by the consumers.
// ---------------------------------------------------------------------------
__global__ __launch_bounds__(256, 1) void u_kernel(
    const float* __restrict__ s2, const short* __restrict__ planes,
    float* __restrict__ Ucr, float* __restrict__ Utm)
{
    __shared__ short actH[64 * 264];
    __shared__ short actM[64 * 264];
    __shared__ short actL[64 * 264];
    const int tid = threadIdx.x;
    const int row0 = blockIdx.x * 64;
    const int wv = tid >> 6, ln = tid & 63;
    for (int i = wv * 16; i < wv * 16 + 16; ++i) {
        int srow = row0 + i; if (srow > 7199) srow = 7199;
        float4 s = *(const float4*)(s2 + srow * 256 + ln * 4);
        float sv[4] = {s.x, s.y, s.z, s.w};
        unsigned short hs[4], ms[4], ls[4];
#pragma unroll
        for (int j = 0; j < 4; ++j) {
            unsigned short h = f2bf(sv[j]); float fh = bf2f(h);
            float r1 = sv[j] - fh;
            unsigned short m = f2bf(r1); float fm = bf2f(m);
            hs[j] = h; ms[j] = m; ls[j] = f2bf(r1 - fm);
        }
        *(short4*)(actH + i * 264 + ln * 4) = make_short4(hs[0], hs[1], hs[2], hs[3]);
        *(short4*)(actM + i * 264 + ln * 4) = make_short4(ms[0], ms[1], ms[2], ms[3]);
        *(short4*)(actL + i * 264 + ln * 4) = make_short4(ls[0], ls[1], ls[2], ls[3]);
    }
    __syncthreads();
    const int ln15 = tid & 15, lng = (tid >> 4) & 3;
    const int wo = (wv * 64 + ln15) * 32 + lng * 8;
    f32x4 acc[4][4];

    // ---- U_cr: 6-pass 3-way (planes 0,1,2) ----
#pragma unroll
    for (int a = 0; a < 4; ++a)
#pragma unroll
        for (int b = 0; b < 4; ++b) acc[a][b] = f32x4{0.f, 0.f, 0.f, 0.f};
#pragma unroll
    for (int kk = 0; kk < 8; ++kk) {
        bf16x8 wH[4], wM[4], wL[4], xH[4], xM[4], xL[4];
#pragma unroll
        for (int ct = 0; ct < 4; ++ct) {
            wH[ct] = *(const bf16x8*)(planes + 0 * PL + wo + kk * 8192 + ct * 512);
            wM[ct] = *(const bf16x8*)(planes + 1 * PL + wo + kk * 8192 + ct * 512);
            wL[ct] = *(const bf16x8*)(planes + 2 * PL + wo + kk * 8192 + ct * 512);
        }
#pragma unroll
        for (int rt = 0; rt < 4; ++rt) {
            int off = (rt * 16 + ln15) * 264 + kk * 32 + lng * 8;
            xH[rt] = *(const bf16x8*)(actH + off);
            xM[rt] = *(const bf16x8*)(actM + off);
            xL[rt] = *(const bf16x8*)(actL + off);
        }
#pragma unroll
        for (int ct = 0; ct < 4; ++ct)
#pragma unroll
            for (int rt = 0; rt < 4; ++rt) {
                acc[ct][rt] = __builtin_amdgcn_mfma_f32_16x16x32_bf16(wH[ct], xH[rt], acc[ct][rt], 0, 0, 0);
                acc[ct][rt] = __builtin_amdgcn_mfma_f32_16x16x32_bf16(wH[ct], xM[rt], acc[ct][rt], 0, 0, 0);
                acc[ct][rt] = __builtin_amdgcn_mfma_f32_16x16x32_bf16(wM[ct], xH[rt], acc[ct][rt], 0, 0, 0);
                acc[ct][rt] = __builtin_amdgcn_mfma_f32_16x16x32_bf16(wM[ct], xM[rt], acc[ct][rt], 0, 0, 0);
                acc[ct][rt] = __builtin_amdgcn_mfma_f32_16x16x32_bf16(wH[ct], xL[rt], acc[ct][rt], 0, 0, 0);
                acc[ct][rt] = __builtin_amdgcn_mfma_f32_16x16x32_bf16(wL[ct], xH[rt], acc[ct][rt], 0, 0, 0);
            }
    }
#pragma unroll
    for (int ct = 0; ct < 4; ++ct)
#pragma unroll
        for (int rt = 0; rt < 4; ++rt) {
            int r = row0 + rt * 16 + ln15;
            if (r < 7200) {
                float4 o; o.x = acc[ct][rt][0]; o.y = acc[ct][rt][1];
                o.z = acc[ct][rt][2]; o.w = acc[ct][rt][3];
                *(float4*)(Ucr + r * 256 + wv * 64 + ct * 16 + lng * 4) = o;
            }
        }

    // ---- U_tm: 3-pass 2-way (planes 6,7) ----
#pragma unroll
    for (int a = 0; a < 4; ++a)
#pragma unroll
        for (int b = 0; b < 4; ++b) acc[a][b] = f32x4{0.f, 0.f, 0.f, 0.f};
#pragma unroll
    for (int kk = 0; kk < 8; ++kk) {
        bf16x8 wH[4], wL[4], xH[4], xM[4];
#pragma unroll
        for (int ct = 0; ct < 4; ++ct) {
            wH[ct] = *(const bf16x8*)(planes + 6 * PL + wo + kk * 8192 + ct * 512);
            wL[ct] = *(const bf16x8*)(planes + 7 * PL + wo + kk * 8192 + ct * 512);
        }
#pragma unroll
        for (int rt = 0; rt < 4; ++rt) {
            int off = (rt * 16 + ln15) * 264 + kk * 32 + lng * 8;
            xH[rt] = *(const bf16x8*)(actH + off);
            xM[rt] = *(const bf16x8*)(actM + off);   // 2-way low == 3-way mid
        }
#pragma unroll
        for (int ct = 0; ct < 4; ++ct)
#pragma unroll
            for (int rt = 0; rt < 4; ++rt) {
                acc[ct][rt] = __builtin_amdgcn_mfma_f32_16x16x32_bf16(wH[ct], xH[rt], acc[ct][rt], 0, 0, 0);
                acc[ct][rt] = __builtin_amdgcn_mfma_f32_16x16x32_bf16(wH[ct], xM[rt], acc[ct][rt], 0, 0, 0);
                acc[ct][rt] = __builtin_amdgcn_mfma_f32_16x16x32_bf16(wL[ct], xH[rt], acc[ct][rt], 0, 0, 0);
            }
    }
#pragma unroll
    for (int ct = 0; ct < 4; ++ct)
#pragma unroll
        for (int rt = 0; rt < 4; ++rt) {
            int r = row0 + rt * 16 + ln15;
            if (r < 7200) {
                float4 o; o.x = acc[ct][rt][0]; o.y = acc[ct][rt][1];
                o.z = acc[ct][rt][2]; o.w = acc[ct][rt][3];
                *(float4*)(Utm + r * 256 + wv * 64 + ct * 16 + lng * 4) = o;
            }
        }
}

// ---------------------------------------------------------------------------
// MFMA stage-3 layers: weights straight to VGPR fragments (L2-resident planes),
// act in LDS (stride 264, conflict-free reads).
// ---------------------------------------------------------------------------

// 2-way split, 3 MFMA passes; 64 rows per block.
template<bool RELU, bool HEAD, bool WRITEACT>
__device__ __forceinline__ void layer_g2(
    const short* __restrict__ plH, const short* __restrict__ plL,
    const float* __restrict__ bias,
    const float* __restrict__ headW, const float* __restrict__ headB,
    float* __restrict__ headOut, int row0,
    short* actH, short* actL, float* hred)
{
    const int tid = threadIdx.x;
    const int ln15 = tid & 15, lng = (tid >> 4) & 3, wv = tid >> 6;
    const int wo = (wv * 64 + ln15) * 32 + lng * 8;   // + ct*512 + kk*8192
    f32x4 acc[4][4];
#pragma unroll
    for (int a = 0; a < 4; ++a)
#pragma unroll
        for (int b = 0; b < 4; ++b) acc[a][b] = f32x4{0.f, 0.f, 0.f, 0.f};

    bf16x8 aH[2][4], aL[2][4];
#pragma unroll
    for (int ct = 0; ct < 4; ++ct) {
        aH[0][ct] = *(const bf16x8*)(plH + wo + ct * 512);
        aL[0][ct] = *(const bf16x8*)(plL + wo + ct * 512);
    }
#pragma unroll
    for (int kk = 0; kk < 8; ++kk) {
        if (kk < 7) {
#pragma unroll
            for (int ct = 0; ct < 4; ++ct) {
                aH[(kk + 1) & 1][ct] = *(const bf16x8*)(plH + wo + (kk + 1) * 8192 + ct * 512);
                aL[(kk + 1) & 1][ct] = *(const bf16x8*)(plL + wo + (kk + 1) * 8192 + ct * 512);
            }
        }
        bf16x8 bH[4], bL[4];
#pragma unroll
        for (int rt = 0; rt < 4; ++rt) {
            int off = (rt * 16 + ln15) * 264 + kk * 32 + lng * 8;
            bH[rt] = *(const bf16x8*)(actH + off);
            bL[rt] = *(const bf16x8*)(actL + off);
        }
#pragma unroll
        for (int ct = 0; ct < 4; ++ct)
#pragma unroll
            for (int rt = 0; rt < 4; ++rt) {
                acc[ct][rt] = __builtin_amdgcn_mfma_f32_16x16x32_bf16(aH[kk & 1][ct], bH[rt], acc[ct][rt], 0, 0, 0);
                acc[ct][rt] = __builtin_amdgcn_mfma_f32_16x16x32_bf16(aH[kk & 1][ct], bL[rt], acc[ct][rt], 0, 0, 0);
                acc[ct][rt] = __builtin_amdgcn_mfma_f32_16x16x32_bf16(aL[kk & 1][ct], bH[rt], acc[ct][rt], 0, 0, 0);
            }
    }
    __syncthreads();   // all act reads done before in-place overwrite

    float hp[4] = {0.f, 0.f, 0.f, 0.f};
#pragma unroll
    for (int ct = 0; ct < 4; ++ct) {
        const int colb = wv * 64 + ct * 16 + lng * 4;
        const float4 bb = *(const float4*)(bias + colb);
#pragma unroll
        for (int rt = 0; rt < 4; ++rt) {
            f32x4 v = acc[ct][rt];
            v[0] += bb.x; v[1] += bb.y; v[2] += bb.z; v[3] += bb.w;
            if (RELU) {
#pragma unroll
                for (int j = 0; j < 4; ++j) v[j] = fmaxf(v[j], 0.f);
            }
            if (HEAD) {
#pragma unroll
                for (int j = 0; j < 4; ++j) hp[rt] += v[j] * headW[colb + j];
            }
            if (WRITEACT) {
                unsigned short hs[4], ls[4];
#pragma unroll
                for (int j = 0; j < 4; ++j) {
                    unsigned short h = f2bf(v[j]); float fh = bf2f(h);
                    hs[j] = h; ls[j] = f2bf(v[j] - fh);
                }
                const int ao = (rt * 16 + ln15) * 264 + colb;
                *(short4*)(actH + ao) = make_short4(hs[0], hs[1], hs[2], hs[3]);
                *(short4*)(actL + ao) = make_short4(ls[0], ls[1], ls[2], ls[3]);
            }
        }
    }
    if constexpr (HEAD) {
#pragma unroll
        for (int rt = 0; rt < 4; ++rt) {
            hp[rt] += __shfl_xor(hp[rt], 16);
            hp[rt] += __shfl_xor(hp[rt], 32);
        }
        if (lng == 0) {
#pragma unroll
            for (int rt = 0; rt < 4; ++rt) hred[wv * 64 + rt * 16 + ln15] = hp[rt];
        }
        __syncthreads();
        if (tid < 64) {
            float s = hred[tid] + hred[64 + tid] + hred[128 + tid] + hred[192 + tid] + headB[0];
            int r = row0 + tid;
            if (r < 108000) headOut[r] = s;
        }
    }
    if constexpr (WRITEACT) __syncthreads();
}

// 3-way split, 6 MFMA passes; 32 rows per block (mask-grade precision).
template<bool HEAD, bool WRITEACT>
__device__ __forceinline__ void layer_g3(
    const short* __restrict__ plH, const short* __restrict__ plM, const short* __restrict__ plL,
    const float* __restrict__ bias,
    const float* __restrict__ headW, int headStride, const float* __restrict__ headB,
    float* __restrict__ headOut, int row0,
    short* actH, short* actM, short* actL, float* hred)
{
    const int tid = threadIdx.x;
    const int ln15 = tid & 15, lng = (tid >> 4) & 3, wv = tid >> 6;
    const int wo = (wv * 64 + ln15) * 32 + lng * 8;
    f32x4 acc[4][2];
#pragma unroll
    for (int a = 0; a < 4; ++a) { acc[a][0] = f32x4{0.f,0.f,0.f,0.f}; acc[a][1] = f32x4{0.f,0.f,0.f,0.f}; }

#pragma unroll
    for (int kk = 0; kk < 8; ++kk) {
        bf16x8 wH[4], wM[4], wL[4], xH[2], xM[2], xL[2];
#pragma unroll
        for (int ct = 0; ct < 4; ++ct) {
            wH[ct] = *(const bf16x8*)(plH + wo + kk * 8192 + ct * 512);
            wM[ct] = *(const bf16x8*)(plM + wo + kk * 8192 + ct * 512);
            wL[ct] = *(const bf16x8*)(plL + wo + kk * 8192 + ct * 512);
        }
#pragma unroll
        for (int rt = 0; rt < 2; ++rt) {
            int off = (rt * 16 + ln15) * 264 + kk * 32 + lng * 8;
            xH[rt] = *(const bf16x8*)(actH + off);
            xM[rt] = *(const bf16x8*)(actM + off);
            xL[rt] = *(const bf16x8*)(actL + off);
        }
#pragma unroll
        for (int ct = 0; ct < 4; ++ct)
#pragma unroll
            for (int rt = 0; rt < 2; ++rt) {
                acc[ct][rt] = __builtin_amdgcn_mfma_f32_16x16x32_bf16(wH[ct], xH[rt], acc[ct][rt], 0, 0, 0);
                acc[ct][rt] = __builtin_amdgcn_mfma_f32_16x16x32_bf16(wH[ct], xM[rt], acc[ct][rt], 0, 0, 0);
                acc[ct][rt] = __builtin_amdgcn_mfma_f32_16x16x32_bf16(wM[ct], xH[rt], acc[ct][rt], 0, 0, 0);
                acc[ct][rt] = __builtin_amdgcn_mfma_f32_16x16x32_bf16(wM[ct], xM[rt], acc[ct][rt], 0, 0, 0);
                acc[ct][rt] = __builtin_amdgcn_mfma_f32_16x16x32_bf16(wH[ct], xL[rt], acc[ct][rt], 0, 0, 0);
                acc[ct][rt] = __builtin_amdgcn_mfma_f32_16x16x32_bf16(wL[ct], xH[rt], acc[ct][rt], 0, 0, 0);
            }
    }
    __syncthreads();

    float hp[2] = {0.f, 0.f};
#pragma unroll
    for (int ct = 0; ct < 4; ++ct) {
        const int colb = wv * 64 + ct * 16 + lng * 4;
        const float4 bb = *(const float4*)(bias + colb);
#pragma unroll
        for (int rt = 0; rt < 2; ++rt) {
            f32x4 v = acc[ct][rt];
            v[0] += bb.x; v[1] += bb.y; v[2] += bb.z; v[3] += bb.w;
#pragma unroll
            for (int j = 0; j < 4; ++j) v[j] = fmaxf(v[j], 0.f);   // both cr layers are relu
            if (HEAD) {
#pragma unroll
                for (int j = 0; j < 4; ++j) hp[rt] += v[j] * headW[(colb + j) * headStride];
            }
            if (WRITEACT) {
                unsigned short hs[4], ms[4], ls[4];
#pragma unroll
                for (int j = 0; j < 4; ++j) {
                    unsigned short h = f2bf(v[j]); float fh = bf2f(h);
                    float r1 = v[j] - fh;
                    unsigned short m = f2bf(r1); float fm = bf2f(m);
                    hs[j] = h; ms[j] = m; ls[j] = f2bf(r1 - fm);
                }
                const int ao = (rt * 16 + ln15) * 264 + colb;
                *(short4*)(actH + ao) = make_short4(hs[0], hs[1], hs[2], hs[3]);
                *(short4*)(actM + ao) = make_short4(ms[0], ms[1], ms[2], ms[3]);
                *(short4*)(actL + ao) = make_short4(ls[0], ls[1], ls[2], ls[3]);
            }
        }
    }
    if constexpr (HEAD) {
#pragma unroll
        for (int rt = 0; rt < 2; ++rt) {
            hp[rt] += __shfl_xor(hp[rt], 16);
            hp[rt] += __shfl_xor(hp[rt], 32);
        }
        if (lng == 0) {
#pragma unroll
            for (int rt = 0; rt < 2; ++rt) hred[wv * 32 + rt * 16 + ln15] = hp[rt];
        }
        __syncthreads();
        if (tid < 32) {
            float s = hred[tid] + hred[32 + tid] + hred[64 + tid] + hred[96 + tid] + headB[0];
            int r = row0 + tid;
            if (r < 108000) headOut[r] = s;
        }
    }
    if constexpr (WRITEACT) __syncthreads();
}

// k3b: stage from U_tm (+rank1+bias+relu, 2-way split), then 5 MFMA layers.
__global__ __launch_bounds__(256, 2) void k3b_kernel(
    const float* __restrict__ Utm, const short* __restrict__ planes,
    const float* __restrict__ tmW0, const float* __restrict__ tmB0,
    const float* __restrict__ tmB1, const float* __restrict__ tmB2,
    const float* __restrict__ emB0, const float* __restrict__ emB1, const float* __restrict__ emB2,
    const float* __restrict__ vW, const float* __restrict__ vb,
    float* __restrict__ Vns3)
{
    __shared__ short actH[64 * 264];
    __shared__ short actL[64 * 264];
    __shared__ float hred[256];
    const int tid = threadIdx.x;
    const int row0 = blockIdx.x * 64;
    const int wv = tid >> 6, ln = tid & 63;
    const float4 wr = *(const float4*)(tmW0 + 65536 + ln * 4);
    const float4 bb = *(const float4*)(tmB0 + ln * 4);
    for (int i = wv * 16; i < wv * 16 + 16; ++i) {
        int r = row0 + i;
        int srow = r / 15; if (srow > 7199) srow = 7199;
        float a = (float)(r % 15);
        float4 u = *(const float4*)(Utm + srow * 256 + ln * 4);
        float sv[4];
        sv[0] = fmaxf(u.x + a * wr.x + bb.x, 0.f);
        sv[1] = fmaxf(u.y + a * wr.y + bb.y, 0.f);
        sv[2] = fmaxf(u.z + a * wr.z + bb.z, 0.f);
        sv[3] = fmaxf(u.w + a * wr.w + bb.w, 0.f);
        unsigned short hs[4], ls[4];
#pragma unroll
        for (int j = 0; j < 4; ++j) {
            unsigned short h = f2bf(sv[j]); float fh = bf2f(h);
            hs[j] = h; ls[j] = f2bf(sv[j] - fh);
        }
        *(short4*)(actH + i * 264 + ln * 4) = make_short4(hs[0], hs[1], hs[2], hs[3]);
        *(short4*)(actL + i * 264 + ln * 4) = make_short4(ls[0], ls[1], ls[2], ls[3]);
    }
    __syncthreads();
    const short* P = planes;
    layer_g2<true,  false, true >(P + 8 * PL,  P + 9 * PL,  tmB1, nullptr, nullptr, nullptr, row0, actH, actL, hred);
    layer_g2<false, false, true >(P + 10 * PL, P + 11 * PL, tmB2, nullptr, nullptr, nullptr, row0, actH, actL, hred);
    layer_g2<true,  false, true >(P + 12 * PL, P + 13 * PL, emB0, nullptr, nullptr, nullptr, row0, actH, actL, hred);
    layer_g2<true,  false, true >(P + 14 * PL, P + 15 * PL, emB1, nullptr, nullptr, nullptr, row0, actH, actL, hred);
    layer_g2<false, true,  false>(P + 16 * PL, P + 17 * PL, emB2, vW, vb, Vns3, row0, actH, actL, hred);
}

// k3a: stage from U_cr (+rank1+bias+relu, 3-way split), then 1 MFMA layer + head.
__global__ __launch_bounds__(256, 3) void k3a_kernel(
    const float* __restrict__ Ucr, const short* __restrict__ planes,
    const float* __restrict__ crW0, const float* __restrict__ crB0,
    const float* __restrict__ crB1, const float* __restrict__ crW2,
    const float* __restrict__ crB2, float* __restrict__ cont2)
{
    __shared__ short actH[32 * 264];
    __shared__ short actM[32 * 264];
    __shared__ short actL[32 * 264];
    __shared__ float hred[128];
    const int tid = threadIdx.x;
    const int row0 = blockIdx.x * 32;
    const int wv = tid >> 6, ln = tid & 63;
    const float4 wr = *(const float4*)(crW0 + 65536 + ln * 4);
    const float4 bb = *(const float4*)(crB0 + ln * 4);
    for (int i = wv * 8; i < wv * 8 + 8; ++i) {
        int r = row0 + i;
        int srow = r / 15; if (srow > 7199) srow = 7199;
        float a = (float)(r % 15);
        float4 u = *(const float4*)(Ucr + srow * 256 + ln * 4);
        float sv[4];
        sv[0] = fmaxf(u.x + a * wr.x + bb.x, 0.f);
        sv[1] = fmaxf(u.y + a * wr.y + bb.y, 0.f);
        sv[2] = fmaxf(u.z + a * wr.z + bb.z, 0.f);
        sv[3] = fmaxf(u.w + a * wr.w + bb.w, 0.f);
        unsigned short hs[4], ms[4], ls[4];
#pragma unroll
        for (int j = 0; j < 4; ++j) {
            unsigned short h = f2bf(sv[j]); float fh = bf2f(h);
            float r1 = sv[j] - fh;
            unsigned short m = f2bf(r1); float fm = bf2f(m);
            hs[j] = h; ms[j] = m; ls[j] = f2bf(r1 - fm);
        }
        *(short4*)(actH + i * 264 + ln * 4) = make_short4(hs[0], hs[1], hs[2], hs[3]);
        *(short4*)(actM + i * 264 + ln * 4) = make_short4(ms[0], ms[1], ms[2], ms[3]);
        *(short4*)(actL + i * 264 + ln * 4) = make_short4(ls[0], ls[1], ls[2], ls[3]);
    }
    __syncthreads();
    const short* P = planes;
    layer_g3<true, false>(P + 3 * PL, P + 4 * PL, P + 5 * PL, crB1,
                          crW2, 2, crB2, cont2, row0, actH, actM, actL, hred);
}

extern "C" void kernel_launch(void* const* d_in, const int* in_sizes, int n_in,
                              void* d_out, int out_size, void* d_ws, size_t ws_size,
                              hipStream_t stream)
{
    (void)in_sizes; (void)n_in; (void)out_size; (void)ws_size;
    const float* x    = (const float*)d_in[0];
    const float* emW0 = (const float*)d_in[1];
    const float* emB0 = (const float*)d_in[2];
    const float* emW1 = (const float*)d_in[3];
    const float* emB1 = (const float*)d_in[4];
    const float* emW2 = (const float*)d_in[5];
    const float* emB2 = (const float*)d_in[6];
    const float* vW   = (const float*)d_in[7];
    const float* vb   = (const float*)d_in[8];
    const float* crW0 = (const float*)d_in[9];
    const float* crB0 = (const float*)d_in[10];
    const float* crW1 = (const float*)d_in[11];
    const float* crB1 = (const float*)d_in[12];
    const float* crW2 = (const float*)d_in[13];
    const float* crB2 = (const float*)d_in[14];
    const float* tmW0 = (const float*)d_in[15];
    const float* tmB0 = (const float*)d_in[16];
    const float* tmW1 = (const float*)d_in[17];
    const float* tmB1 = (const float*)d_in[18];
    const float* tmW2 = (const float*)d_in[19];
    const float* tmB2 = (const float*)d_in[20];
    float* out = (float*)d_out;

    float* w     = (float*)d_ws;
    float* rews0 = w;                     // 480
    float* cont1 = rews0 + 480;           // 7200
    float* rews1 = cont1 + 7200;          // 7200
    float* cont2 = rews1 + 7200;          // 108000
    float* Vns3  = cont2 + 108000;        // 108000
    float* s1    = Vns3 + 108000;         // 480*256
    float* s2    = s1 + 480 * 256;        // 7200*256
    short* planes = (short*)(s2 + 7200 * 256);  // 18 * 65536 shorts = 2.25 MB
    float* Ucr   = (float*)(planes + 18 * PL);  // 7200*256
    float* Utm   = Ucr + 7200 * 256;            // 7200*256

    constexpr int TM = 24;
    prep_kernel<<<64, 256, 0, stream>>>(crW0, crW1, tmW0, tmW1, tmW2, emW0, emW1, emW2, planes);
    value_x_kernel<<<1, 256, 0, stream>>>(x, emW0, emB0, emW1, emB1, emW2, emB2, vW, vb, out + NB * NA);
    stage1_kernel<TM><<<480 / TM, 256, 0, stream>>>(x,
        crW0, crB0, crW1, crB1, crW2, crB2,
        tmW0, tmB0, tmW1, tmB1, tmW2, tmB2, s1, rews0);
    stage2_kernel<TM><<<7200 / TM, 256, 0, stream>>>(s1,
        crW0, crB0, crW1, crB1, crW2, crB2,
        tmW0, tmB0, tmW1, tmB1, tmW2, tmB2, s2, cont1, rews1);
    u_kernel<<<(7200 + 63) / 64, 256, 0, stream>>>(s2, planes, Ucr, Utm);
    k3a_kernel<<<108000 / 32, 256, 0, stream>>>(Ucr, planes, crW0, crB0, crB1, crW2, crB2, cont2);
    k3b_kernel<<<(108000 + 63) / 64, 256, 0, stream>>>(Utm, planes, tmW0,
        tmB0, tmB1, tmB2, emB0, emB1, emB2, vW, vb, Vns3);
    finalize_kernel<<<NB, 256, 0, stream>>>(Vns3, cont2, rews0, rews1, cont1, out);
}